// Round 6
// baseline (260.684 us; speedup 1.0000x reference)
//
#include <hip/hip_runtime.h>
#include <stdint.h>
#include <math.h>

typedef unsigned short u16;
typedef __bf16 bf16x8 __attribute__((ext_vector_type(8)));
typedef float f32x4 __attribute__((ext_vector_type(4)));

// fp32 -> bf16 round-to-nearest-even, bit-level
__device__ __forceinline__ u16 f2bf(float f) {
    union { float f; unsigned int u; } a; a.f = f;
    unsigned int u = a.u;
    u += 0x7FFFu + ((u >> 16) & 1u);
    return (u16)(u >> 16);
}

__device__ __forceinline__ void async_load16(const void* g, void* l) {
    __builtin_amdgcn_global_load_lds(
        (const __attribute__((address_space(1))) void*)g,
        (__attribute__((address_space(3))) void*)l,
        16, 0, 0);
}

// ---------------------------------------------------------------------------
// Fragment layout (HW-verified by the working LDS kernel):
//   A-frag (16x16x32 bf16): lane l holds row = l&15, k = kchunk*32 + (l>>4)*8 + e
//   B-frag:                 lane l holds col = l&15, k = kchunk*32 + (l>>4)*8 + e
// E is stored frag-packed: per 128x128 tri tile, 32 frag-blocks of 1KB:
//   block (r16, kk) at offset ((r16*4+kk)*512 u16); lane*8 within.
// Vf is V in B-frag order: block (d16, kt) of 1KB at ((d16*(T/32)+kt)*512).
// ---------------------------------------------------------------------------

// ---------------------------------------------------------------------------
// gemm_score: R0-structure 64x128 score tile (2-barrier, 24KB LDS, high TLP).
// Epilogue: exp2 + causal mask + rowsum atomics; E emitted FRAG-PACKED via a
// wave-private XOR-swizzled LDS transpose (Bs reused post-loop), coalesced
// 16B stores.
// ---------------------------------------------------------------------------
__device__ __forceinline__ void gemm_score(
    const u16* __restrict__ A, const u16* __restrict__ Bt,
    u16* __restrict__ Etile, float* __restrict__ rowsum,
    int bm, int bn, int bz, int M, int K, float kfac,
    u16* As, u16* Bs)
{
    constexpr int KB = 64;
    const int tid  = threadIdx.x;
    const int lane = tid & 63;
    const int wv   = tid >> 6;
    const int wm   = wv >> 1;
    const int wn   = wv & 1;

    f32x4 acc[2][4] = {};

    const int rowA0 = bm * 64, rowB0 = bn * 128;
    const int lrow  = lane >> 3;
    const int lslot = lane & 7;
    const int sg    = (lslot ^ lrow) * 8;

    const int lm   = lane & 15;
    const int quad = lane >> 4;
    const int rx   = lm & 7;

    for (int k0 = 0; k0 < K; k0 += KB) {
        #pragma unroll
        for (int c = 0; c < 2; ++c) {
            const int cc  = wv * 2 + c;
            const int row = cc * 8 + lrow;
            async_load16(&A[(size_t)(rowA0 + row) * K + k0 + sg], &As[cc * 512 + lane * 8]);
        }
        #pragma unroll
        for (int c = 0; c < 4; ++c) {
            const int cc  = wv * 4 + c;
            const int row = cc * 8 + lrow;
            async_load16(&Bt[(size_t)(rowB0 + row) * K + k0 + sg], &Bs[cc * 512 + lane * 8]);
        }
        __syncthreads();

        #pragma unroll
        for (int h = 0; h < 2; ++h) {
            const int sl = (((h * 4 + quad) ^ rx) * 8);
            bf16x8 af[2], bfr[4];
            #pragma unroll
            for (int i = 0; i < 2; ++i)
                af[i] = *reinterpret_cast<const bf16x8*>(
                    &As[(wm * 32 + i * 16 + lm) * KB + sl]);
            #pragma unroll
            for (int j = 0; j < 4; ++j)
                bfr[j] = *reinterpret_cast<const bf16x8*>(
                    &Bs[(wn * 64 + j * 16 + lm) * KB + sl]);
            #pragma unroll
            for (int i = 0; i < 2; ++i)
                #pragma unroll
                for (int j = 0; j < 4; ++j)
                    acc[i][j] = __builtin_amdgcn_mfma_f32_16x16x32_bf16(af[i], bfr[j], acc[i][j], 0, 0, 0);
        }
        __syncthreads();
    }

    // ---- epilogue ----
    // C/D layout (m89-verified): col = lane&15, row = quad*4 + g.
    // Stash exp'd bf16 into wave-private LDS patch (32x64, XOR col swizzle),
    // then emit frag-blocks with coalesced 16B stores.
    u16* patch = Bs + wv * 2048;     // 4 waves x 2048 u16 = Bs exactly
    float rs[2][4];
    #pragma unroll
    for (int i = 0; i < 2; ++i)
        #pragma unroll
        for (int g = 0; g < 4; ++g) rs[i][g] = 0.f;
    #pragma unroll
    for (int i = 0; i < 2; ++i)
        #pragma unroll
        for (int j = 0; j < 4; ++j) {
            const int cl = j * 16 + lm;                       // col within wave's 64
            const int c  = rowB0 + wn * 64 + cl;              // global col
            #pragma unroll
            for (int g = 0; g < 4; ++g) {
                const int rl = i * 16 + quad * 4 + g;         // row within wave's 32
                const int r  = rowA0 + wm * 32 + rl;          // global row
                float e = (c <= r) ? exp2f(acc[i][j][g] * kfac) : 0.f;
                patch[rl * 64 + (cl ^ ((rl & 7) << 3))] = f2bf(e);
                rs[i][g] += e;
            }
        }
    #pragma unroll
    for (int i = 0; i < 2; ++i)
        #pragma unroll
        for (int g = 0; g < 4; ++g) {
            float v = rs[i][g];
            v += __shfl_xor(v, 1); v += __shfl_xor(v, 2);
            v += __shfl_xor(v, 4); v += __shfl_xor(v, 8);
            rs[i][g] = v;
        }
    if (lm == 0) {
        #pragma unroll
        for (int i = 0; i < 2; ++i)
            #pragma unroll
            for (int g = 0; g < 4; ++g) {
                const int r = rowA0 + wm * 32 + i * 16 + quad * 4 + g;
                atomicAdd(&rowsum[(size_t)bz * M + r], rs[i][g]);
            }
    }
    // frag emission (wave-private patch; same-wave LDS dep handled by compiler)
    const int r16b = ((rowA0 & 127) >> 4) + wm * 2;   // (bm&1)*4 + wm*2
    #pragma unroll
    for (int i2 = 0; i2 < 2; ++i2)
        #pragma unroll
        for (int kk = 0; kk < 2; ++kk) {
            const int row_l = i2 * 16 + lm;
            const int colsw = (kk * 32 + quad * 8) ^ (rx << 3);
            bf16x8 v = *reinterpret_cast<const bf16x8*>(&patch[row_l * 64 + colsw]);
            *reinterpret_cast<bf16x8*>(
                &Etile[(size_t)((((r16b + i2) << 2) + wn * 2 + kk) << 9) + lane * 8]) = v;
        }
}

// ---------------------------------------------------------------------------
// k_qkv2: counted-vmcnt triple-buffered GEMM. 128x256 tile, 8 waves, KB=64.
// 3 LDS buffers of 48KB. Measured 61-63 us — kept as-is.
// ---------------------------------------------------------------------------
__global__ __launch_bounds__(512, 2)
void k_qkv2(const u16* __restrict__ Xb, const u16* __restrict__ Wt,
            u16* __restrict__ Q, int M, int N, int K)
{
    extern __shared__ __attribute__((aligned(16))) u16 S[];
    const int tid  = threadIdx.x;
    const int lane = tid & 63;
    const int wv   = tid >> 6;
    const int wm   = wv >> 2;
    const int wn   = wv & 3;
    const int bn   = blockIdx.x;
    const int bm   = blockIdx.y;
    const int rowA0 = bm * 128, rowB0 = bn * 256;

    const int lrow  = lane >> 3;
    const int lslot = lane & 7;
    const int sg    = (lslot ^ lrow) * 8;
    const int lm    = lane & 15;
    const int quad  = lane >> 4;
    const int rx    = lm & 7;

    f32x4 acc[4][4] = {};
    const int nt = K >> 6;

    auto stage = [&](int t, int b) {
        u16* As = S + b * 24576;
        u16* Bs = As + 8192;
        const int k0 = t << 6;
        #pragma unroll
        for (int c = 0; c < 2; ++c) {
            const int cc  = wv * 2 + c;
            const int row = cc * 8 + lrow;
            async_load16(&Xb[(size_t)(rowA0 + row) * K + k0 + sg], &As[cc * 512 + lane * 8]);
        }
        #pragma unroll
        for (int c = 0; c < 4; ++c) {
            const int cc  = wv * 4 + c;
            const int row = cc * 8 + lrow;
            async_load16(&Wt[(size_t)(rowB0 + row) * K + k0 + sg], &Bs[cc * 512 + lane * 8]);
        }
    };

    auto compute = [&](int b) {
        const u16* As = S + b * 24576;
        const u16* Bs = As + 8192;
        #pragma unroll
        for (int h = 0; h < 2; ++h) {
            const int sl = (((h * 4 + quad) ^ rx) * 8);
            bf16x8 af[4], bfr[4];
            #pragma unroll
            for (int i = 0; i < 4; ++i)
                af[i] = *reinterpret_cast<const bf16x8*>(
                    &As[(wm * 64 + i * 16 + lm) * 64 + sl]);
            #pragma unroll
            for (int j = 0; j < 4; ++j)
                bfr[j] = *reinterpret_cast<const bf16x8*>(
                    &Bs[(wn * 64 + j * 16 + lm) * 64 + sl]);
            #pragma unroll
            for (int i = 0; i < 4; ++i)
                #pragma unroll
                for (int j = 0; j < 4; ++j)
                    acc[i][j] = __builtin_amdgcn_mfma_f32_16x16x32_bf16(af[i], bfr[j], acc[i][j], 0, 0, 0);
        }
    };

    stage(0, 0);
    stage(1, 1);
    asm volatile("s_waitcnt vmcnt(6)" ::: "memory");
    __builtin_amdgcn_s_barrier();

    int cb = 0;
    #pragma unroll 1
    for (int t = 0; t < nt - 2; ++t) {
        int sb = cb + 2; if (sb >= 3) sb -= 3;
        stage(t + 2, sb);
        compute(cb);
        asm volatile("s_waitcnt vmcnt(6)" ::: "memory");
        __builtin_amdgcn_s_barrier();
        if (++cb == 3) cb = 0;
    }
    compute(cb);
    asm volatile("s_waitcnt vmcnt(0)" ::: "memory");
    __builtin_amdgcn_s_barrier();
    if (++cb == 3) cb = 0;
    compute(cb);

    u16* C = Q + (size_t)(bn >> 2) * ((size_t)M * 1024);
    const int cbase = (rowB0 & 1023) + wn * 64;
    #pragma unroll
    for (int i = 0; i < 4; ++i)
        #pragma unroll
        for (int j = 0; j < 4; ++j) {
            const int r0 = rowA0 + wm * 64 + i * 16 + quad * 4;
            const int c0 = cbase + j * 16 + lm;
            #pragma unroll
            for (int g = 0; g < 4; ++g)
                C[(size_t)(r0 + g) * 1024 + c0] = f2bf(acc[i][j][g]);
        }
}

// S (tri 64x128 blocks -> frag-packed E) + V -> B-frag-packed Vf (tail blocks)
__global__ __launch_bounds__(256)
void k_score_vt(const u16* __restrict__ Q, const u16* __restrict__ Kb,
                u16* __restrict__ Epk, float* __restrict__ rowsum,
                const u16* __restrict__ Vb, u16* __restrict__ Vf,
                int T, int D, float kfac, int nTri)
{
    __shared__ __attribute__((aligned(16))) u16 As[64 * 64];
    __shared__ __attribute__((aligned(16))) u16 Bs[128 * 64];
    __shared__ u16 tt[32][33];
    const int bz = blockIdx.z;

    if ((int)blockIdx.x < nTri) {
        // 64-row tri decode (R0-verified): covers bn <= bm/2
        const int idx = blockIdx.x;
        int w = (int)sqrtf((float)idx + 0.5f);
        while (w * w > idx) --w;
        while ((w + 1) * (w + 1) <= idx) ++w;
        int bm, bn;
        if (idx < w * w + w) { bm = 2 * w - 1; bn = idx - w * w; }
        else                 { bm = 2 * w;     bn = idx - (w * w + w); }
        const int bm128 = bm >> 1;
        const int tile  = bm128 * (bm128 + 1) / 2 + bn;
        u16* Etile = Epk + ((size_t)bz * 136 + tile) * 16384;
        gemm_score(Q + (size_t)bz * T * D, Kb + (size_t)bz * T * D,
                   Etile, rowsum, bm, bn, bz, T, D, kfac, As, Bs);
    } else {
        const int t  = blockIdx.x - nTri;
        const int cx = t & 31;          // D/32 tiles
        const int cy = t >> 5;          // T/32 tiles
        const u16* V = Vb + (size_t)bz * T * D;
        u16*      Vo = Vf + (size_t)bz * ((size_t)D * T);
        const int c0 = cx * 32, r0 = cy * 32;
        const int tx = threadIdx.x & 31, ty = threadIdx.x >> 5;
        #pragma unroll
        for (int s = 0; s < 32; s += 8)
            tt[ty + s][tx] = V[(size_t)(r0 + ty + s) * D + c0 + tx];   // tt[t][d]
        __syncthreads();
        if (threadIdx.x < 128) {
            const int l  = threadIdx.x & 63;
            const int f  = threadIdx.x >> 6;          // which 16-d half
            const int dl = f * 16 + (l & 15);
            const int tb = (l >> 4) * 8;
            union { u16 u[8]; float4 v; } r;
            #pragma unroll
            for (int e = 0; e < 8; ++e) r.u[e] = tt[tb + e][dl];
            const int d16g = cx * 2 + f;
            *reinterpret_cast<float4*>(
                &Vo[(size_t)((d16g * (T / 32) + cy) << 9) + l * 8]) = r.v;
        }
    }
}

// ---------------------------------------------------------------------------
// k_pv2: NO LDS, NO barriers. E (frag-packed) and Vf (B-frag-packed) loaded
// straight global->VGPR with fully-coalesced 1KB-per-wave fragment loads.
// 64x128 out tile, 4 waves 2x2; per 32-k step: 6 loads + 8 MFMA.
// Latency hidden by occupancy (no LDS) + ILP, not barriers.
// ---------------------------------------------------------------------------
__global__ __launch_bounds__(256)
void k_pv2(const u16* __restrict__ Epk, const u16* __restrict__ Vf,
           float* __restrict__ out, const float* __restrict__ rowsum,
           int T, int D)
{
    const int bz   = blockIdx.z;
    const int bm   = (gridDim.y - 1) - blockIdx.y;   // 64-row block, heavy-first
    const int bn   = blockIdx.x;                     // D/128
    const int tid  = threadIdx.x;
    const int lane = tid & 63;
    const int wv   = tid >> 6;
    const int wm   = wv >> 1;
    const int wn   = wv & 1;
    const int lm   = lane & 15;
    const int quad = lane >> 4;

    const int bm128 = bm >> 1;
    const u16* Etri = Epk + ((size_t)bz * 136 + (size_t)bm128 * (bm128 + 1) / 2) * 16384;
    const int r16b  = ((bm & 1) << 2) + wm * 2;      // r16 base within 128-tile
    const int kEnd  = (bm + 1) * 64;
    const u16* vfb  = Vf + (size_t)bz * ((size_t)D * T);
    const int  TS   = T >> 5;                        // 64 kt blocks

    f32x4 acc[2][4] = {};

    #pragma unroll 2
    for (int k0 = 0; k0 < kEnd; k0 += 32) {
        const u16* tb = Etri + (size_t)(k0 >> 7) * 16384;
        const int  kk = (k0 >> 5) & 3;
        const int  kt = k0 >> 5;
        bf16x8 af[2], bf[4];
        #pragma unroll
        for (int i = 0; i < 2; ++i)
            af[i] = *reinterpret_cast<const bf16x8*>(
                &tb[(size_t)(((((r16b + i) << 2) + kk)) << 9) + lane * 8]);
        #pragma unroll
        for (int j = 0; j < 4; ++j) {
            const int d16 = (bn << 3) + (wn << 2) + j;
            bf[j] = *reinterpret_cast<const bf16x8*>(
                &vfb[(size_t)((d16 * TS + kt) << 9) + lane * 8]);
        }
        #pragma unroll
        for (int i = 0; i < 2; ++i)
            #pragma unroll
            for (int j = 0; j < 4; ++j)
                acc[i][j] = __builtin_amdgcn_mfma_f32_16x16x32_bf16(af[i], bf[j], acc[i][j], 0, 0, 0);
    }

    // epilogue: divide by rowsum, write out (C/D layout col=lm, row=quad*4+g)
    const int rowA0 = bm * 64;
    float* C = out + (size_t)bz * ((size_t)T * D);
    #pragma unroll
    for (int i = 0; i < 2; ++i) {
        const int r0 = rowA0 + wm * 32 + i * 16 + quad * 4;
        float inv[4];
        #pragma unroll
        for (int g = 0; g < 4; ++g)
            inv[g] = 1.f / rowsum[(size_t)bz * T + r0 + g];
        #pragma unroll
        for (int j = 0; j < 4; ++j) {
            const int c0 = (bn << 7) + wn * 64 + j * 16 + lm;
            #pragma unroll
            for (int g = 0; g < 4; ++g)
                C[(size_t)(r0 + g) * D + c0] = acc[i][j][g] * inv[g];
        }
    }
}

// prep: cast_x (blocks [0,nCX)) + W transpose-cast ([nCX,nCX+nW)) + RS zero
__global__ __launch_bounds__(256)
void k_prep(const float* __restrict__ x,
            const float* __restrict__ W0, const float* __restrict__ W1,
            const float* __restrict__ W2,
            u16* __restrict__ Xb, u16* __restrict__ Wt, float* __restrict__ RS,
            int D, int nCX, int nW)
{
    const int bx = blockIdx.x;
    if (bx < nCX) {
        long long i = ((long long)bx * 256 + threadIdx.x) * 8;
        const float4 a = *(const float4*)(x + i);
        const float4 b = *(const float4*)(x + i + 4);
        union { u16 u[8]; float4 v; } r;
        r.u[0] = f2bf(a.x); r.u[1] = f2bf(a.y); r.u[2] = f2bf(a.z); r.u[3] = f2bf(a.w);
        r.u[4] = f2bf(b.x); r.u[5] = f2bf(b.y); r.u[6] = f2bf(b.z); r.u[7] = f2bf(b.w);
        *(float4*)(Xb + i) = r.v;
    } else if (bx < nCX + nW) {
        __shared__ u16 t[32][33];
        const int w  = bx - nCX;
        const int z  = w >> 10;                 // 1024 tiles per matrix (32x32)
        const int rm = w & 1023;
        const float* W = z == 0 ? W0 : (z == 1 ? W1 : W2);
        u16* dst = Wt + (size_t)z * D * D;
        const int c0 = (rm & 31) * 32, r0 = (rm >> 5) * 32;
        const int tx = threadIdx.x & 31, ty = threadIdx.x >> 5;
        #pragma unroll
        for (int s = 0; s < 32; s += 8)
            t[ty + s][tx] = f2bf(W[(size_t)(r0 + ty + s) * D + c0 + tx]);
        __syncthreads();
        #pragma unroll
        for (int s = 0; s < 32; s += 8)
            dst[(size_t)(c0 + ty + s) * D + r0 + tx] = t[tx][ty + s];
    } else {
        const int t = bx - nCX - nW;
        ((float4*)RS)[t * 256 + threadIdx.x] = float4{0.f, 0.f, 0.f, 0.f};
    }
}

extern "C" void kernel_launch(void* const* d_in, const int* in_sizes, int n_in,
                              void* d_out, int out_size, void* d_ws, size_t ws_size,
                              hipStream_t stream)
{
    const int B = 4, T = 2048, D = 1024;
    const float* x  = (const float*)d_in[0];
    const float* Wq = (const float*)d_in[1];
    const float* Wk = (const float*)d_in[2];
    const float* Wv = (const float*)d_in[3];
    float* out = (float*)d_out;

    // Workspace layout (86 MB + 32 KB):
    //   [0,16M)   Xb   bf16 x        (dead after k_qkv2)
    //   [16,22M)  Wt   3 x W^T bf16  (dead after k_qkv2)
    //   [0,17.8M) Epk  frag-packed tri E, 4 x 136 tiles x 32KB (aliases Xb/Wt)
    //   [22,38M)  Q    [38,54M) K    [54,70M) V    [70,86M) Vf (B-frag packed)
    //   [86M,+32K) RS  rowsum fp32
    const size_t nX = (size_t)B * T * D;
    u16* Xb  = (u16*)d_ws;
    u16* Wt  = Xb + nX;
    u16* Epk = (u16*)d_ws;                         // alias over Xb+Wt
    u16* Q   = Wt + 3 * (size_t)D * D;
    u16* Kb  = Q + nX;
    u16* Vb  = Kb + nX;
    u16* Vf  = Vb + nX;
    float* RS = (float*)(Vf + nX);

    const float kfac = 1.4426950408889634f / 32.0f;  // log2(e)/sqrt(d_out)
    const int nTri64 = 272;   // sum_{bm=0..31} (bm/2 + 1), 64-row tri tiles
    const int nCX = (int)(nX / (8 * 256));           // 4096 cast blocks
    const int nW  = 3 * (D / 32) * (D / 32);         // 3072 W-transpose blocks
    const int nRS = (B * T) / (4 * 256);             // 8 RS-zero blocks

    static bool attr_done = false;
    if (!attr_done) {
        (void)hipFuncSetAttribute((const void*)k_qkv2,
                                  hipFuncAttributeMaxDynamicSharedMemorySize,
                                  147456);
        attr_done = true;
    }

    // 1. prep: x-cast + W-transpose-cast + RS zero
    k_prep<<<dim3(nCX + nW + nRS), 256, 0, stream>>>(
        x, Wq, Wk, Wv, Xb, Wt, RS, D, nCX, nW);
    // 2. merged QKV projection, counted-vmcnt triple-buffer
    k_qkv2<<<dim3(3 * D / 256, (B * T) / 128), 512, 147456, stream>>>(
        Xb, Wt, Q, B * T, 3 * D, D);
    // 3. S -> frag-packed tri E (272/batch) + V -> B-frag Vf (2048/batch)
    k_score_vt<<<dim3(nTri64 + (D / 32) * (T / 32), 1, B), 256, 0, stream>>>(
        Q, Kb, Epk, RS, Vb, Vf, T, D, kfac, nTri64);
    // 4. PV: LDS-free fragment-direct GEMM, heavy-first
    k_pv2<<<dim3(D / 128, T / 64, B), 256, 0, stream>>>(
        Epk, Vf, out, RS, T, D);
}

// Round 8
// 256.064 us; speedup vs baseline: 1.0180x; 1.0180x over previous
//
#include <hip/hip_runtime.h>
#include <stdint.h>
#include <math.h>

typedef unsigned short u16;
typedef __bf16 bf16x8 __attribute__((ext_vector_type(8)));
typedef float f32x4 __attribute__((ext_vector_type(4)));

// fp32 -> bf16 round-to-nearest-even, bit-level
__device__ __forceinline__ u16 f2bf(float f) {
    union { float f; unsigned int u; } a; a.f = f;
    unsigned int u = a.u;
    u += 0x7FFFu + ((u >> 16) & 1u);
    return (u16)(u >> 16);
}

__device__ __forceinline__ void async_load16(const void* g, void* l) {
    __builtin_amdgcn_global_load_lds(
        (const __attribute__((address_space(1))) void*)g,
        (__attribute__((address_space(3))) void*)l,
        16, 0, 0);
}

// ---------------------------------------------------------------------------
// Fragment layout (HW-verified by the working LDS kernel):
//   A-frag (16x16x32 bf16): lane l holds row = l&15, k = kchunk*32 + (l>>4)*8 + e
//   B-frag:                 lane l holds col = l&15, k = kchunk*32 + (l>>4)*8 + e
// E is stored frag-packed: per 128x128 tri tile, 32 frag-blocks of 1KB:
//   block (r16, kk) at offset ((r16*4+kk)*512 u16); lane*8 within.
// Vf is V in B-frag order: block (d16, kt) of 1KB at ((d16*(T/32)+kt)*512).
// ---------------------------------------------------------------------------

// ---------------------------------------------------------------------------
// gemm_score: R0-structure 64x128 score tile (2-barrier, 24KB LDS, high TLP).
// Epilogue: exp2 + causal mask + rowsum atomics; E emitted FRAG-PACKED via a
// wave-private XOR-swizzled LDS transpose (Bs reused post-loop), coalesced
// 16B stores.
// ---------------------------------------------------------------------------
__device__ __forceinline__ void gemm_score(
    const u16* __restrict__ A, const u16* __restrict__ Bt,
    u16* __restrict__ Etile, float* __restrict__ rowsum,
    int bm, int bn, int bz, int M, int K, float kfac,
    u16* As, u16* Bs)
{
    constexpr int KB = 64;
    const int tid  = threadIdx.x;
    const int lane = tid & 63;
    const int wv   = tid >> 6;
    const int wm   = wv >> 1;
    const int wn   = wv & 1;

    f32x4 acc[2][4] = {};

    const int rowA0 = bm * 64, rowB0 = bn * 128;
    const int lrow  = lane >> 3;
    const int lslot = lane & 7;
    const int sg    = (lslot ^ lrow) * 8;

    const int lm   = lane & 15;
    const int quad = lane >> 4;
    const int rx   = lm & 7;

    for (int k0 = 0; k0 < K; k0 += KB) {
        #pragma unroll
        for (int c = 0; c < 2; ++c) {
            const int cc  = wv * 2 + c;
            const int row = cc * 8 + lrow;
            async_load16(&A[(size_t)(rowA0 + row) * K + k0 + sg], &As[cc * 512 + lane * 8]);
        }
        #pragma unroll
        for (int c = 0; c < 4; ++c) {
            const int cc  = wv * 4 + c;
            const int row = cc * 8 + lrow;
            async_load16(&Bt[(size_t)(rowB0 + row) * K + k0 + sg], &Bs[cc * 512 + lane * 8]);
        }
        __syncthreads();

        #pragma unroll
        for (int h = 0; h < 2; ++h) {
            const int sl = (((h * 4 + quad) ^ rx) * 8);
            bf16x8 af[2], bfr[4];
            #pragma unroll
            for (int i = 0; i < 2; ++i)
                af[i] = *reinterpret_cast<const bf16x8*>(
                    &As[(wm * 32 + i * 16 + lm) * KB + sl]);
            #pragma unroll
            for (int j = 0; j < 4; ++j)
                bfr[j] = *reinterpret_cast<const bf16x8*>(
                    &Bs[(wn * 64 + j * 16 + lm) * KB + sl]);
            #pragma unroll
            for (int i = 0; i < 2; ++i)
                #pragma unroll
                for (int j = 0; j < 4; ++j)
                    acc[i][j] = __builtin_amdgcn_mfma_f32_16x16x32_bf16(af[i], bfr[j], acc[i][j], 0, 0, 0);
        }
        __syncthreads();
    }

    // ---- epilogue ----
    // C/D layout (m89-verified): col = lane&15, row = quad*4 + g.
    // Stash exp'd bf16 into wave-private LDS patch (32x64, XOR col swizzle),
    // then emit frag-blocks with coalesced 16B stores.
    u16* patch = Bs + wv * 2048;     // 4 waves x 2048 u16 = Bs exactly
    float rs[2][4];
    #pragma unroll
    for (int i = 0; i < 2; ++i)
        #pragma unroll
        for (int g = 0; g < 4; ++g) rs[i][g] = 0.f;
    #pragma unroll
    for (int i = 0; i < 2; ++i)
        #pragma unroll
        for (int j = 0; j < 4; ++j) {
            const int cl = j * 16 + lm;                       // col within wave's 64
            const int c  = rowB0 + wn * 64 + cl;              // global col
            #pragma unroll
            for (int g = 0; g < 4; ++g) {
                const int rl = i * 16 + quad * 4 + g;         // row within wave's 32
                const int r  = rowA0 + wm * 32 + rl;          // global row
                float e = (c <= r) ? exp2f(acc[i][j][g] * kfac) : 0.f;
                patch[rl * 64 + (cl ^ ((rl & 7) << 3))] = f2bf(e);
                rs[i][g] += e;
            }
        }
    #pragma unroll
    for (int i = 0; i < 2; ++i)
        #pragma unroll
        for (int g = 0; g < 4; ++g) {
            float v = rs[i][g];
            v += __shfl_xor(v, 1); v += __shfl_xor(v, 2);
            v += __shfl_xor(v, 4); v += __shfl_xor(v, 8);
            rs[i][g] = v;
        }
    if (lm == 0) {
        #pragma unroll
        for (int i = 0; i < 2; ++i)
            #pragma unroll
            for (int g = 0; g < 4; ++g) {
                const int r = rowA0 + wm * 32 + i * 16 + quad * 4 + g;
                atomicAdd(&rowsum[(size_t)bz * M + r], rs[i][g]);
            }
    }
    // frag emission (wave-private patch; same-wave LDS dep handled by compiler)
    const int r16b = ((rowA0 & 127) >> 4) + wm * 2;   // (bm&1)*4 + wm*2
    #pragma unroll
    for (int i2 = 0; i2 < 2; ++i2)
        #pragma unroll
        for (int kk = 0; kk < 2; ++kk) {
            const int row_l = i2 * 16 + lm;
            const int colsw = (kk * 32 + quad * 8) ^ (rx << 3);
            bf16x8 v = *reinterpret_cast<const bf16x8*>(&patch[row_l * 64 + colsw]);
            *reinterpret_cast<bf16x8*>(
                &Etile[(size_t)((((r16b + i2) << 2) + wn * 2 + kk) << 9) + lane * 8]) = v;
        }
}

// ---------------------------------------------------------------------------
// k_qkv2: counted-vmcnt triple-buffered GEMM. 128x256 tile, 8 waves, KB=64.
// 3 LDS buffers of 48KB. Measured 61-63 us — kept as-is.
// ---------------------------------------------------------------------------
__global__ __launch_bounds__(512, 2)
void k_qkv2(const u16* __restrict__ Xb, const u16* __restrict__ Wt,
            u16* __restrict__ Q, int M, int N, int K)
{
    extern __shared__ __attribute__((aligned(16))) u16 S[];
    const int tid  = threadIdx.x;
    const int lane = tid & 63;
    const int wv   = tid >> 6;
    const int wm   = wv >> 2;
    const int wn   = wv & 3;
    const int bn   = blockIdx.x;
    const int bm   = blockIdx.y;
    const int rowA0 = bm * 128, rowB0 = bn * 256;

    const int lrow  = lane >> 3;
    const int lslot = lane & 7;
    const int sg    = (lslot ^ lrow) * 8;
    const int lm    = lane & 15;
    const int quad  = lane >> 4;
    const int rx    = lm & 7;

    f32x4 acc[4][4] = {};
    const int nt = K >> 6;

    auto stage = [&](int t, int b) {
        u16* As = S + b * 24576;
        u16* Bs = As + 8192;
        const int k0 = t << 6;
        #pragma unroll
        for (int c = 0; c < 2; ++c) {
            const int cc  = wv * 2 + c;
            const int row = cc * 8 + lrow;
            async_load16(&Xb[(size_t)(rowA0 + row) * K + k0 + sg], &As[cc * 512 + lane * 8]);
        }
        #pragma unroll
        for (int c = 0; c < 4; ++c) {
            const int cc  = wv * 4 + c;
            const int row = cc * 8 + lrow;
            async_load16(&Wt[(size_t)(rowB0 + row) * K + k0 + sg], &Bs[cc * 512 + lane * 8]);
        }
    };

    auto compute = [&](int b) {
        const u16* As = S + b * 24576;
        const u16* Bs = As + 8192;
        #pragma unroll
        for (int h = 0; h < 2; ++h) {
            const int sl = (((h * 4 + quad) ^ rx) * 8);
            bf16x8 af[4], bfr[4];
            #pragma unroll
            for (int i = 0; i < 4; ++i)
                af[i] = *reinterpret_cast<const bf16x8*>(
                    &As[(wm * 64 + i * 16 + lm) * 64 + sl]);
            #pragma unroll
            for (int j = 0; j < 4; ++j)
                bfr[j] = *reinterpret_cast<const bf16x8*>(
                    &Bs[(wn * 64 + j * 16 + lm) * 64 + sl]);
            #pragma unroll
            for (int i = 0; i < 4; ++i)
                #pragma unroll
                for (int j = 0; j < 4; ++j)
                    acc[i][j] = __builtin_amdgcn_mfma_f32_16x16x32_bf16(af[i], bfr[j], acc[i][j], 0, 0, 0);
        }
    };

    stage(0, 0);
    stage(1, 1);
    asm volatile("s_waitcnt vmcnt(6)" ::: "memory");
    __builtin_amdgcn_s_barrier();

    int cb = 0;
    #pragma unroll 1
    for (int t = 0; t < nt - 2; ++t) {
        int sb = cb + 2; if (sb >= 3) sb -= 3;
        stage(t + 2, sb);
        compute(cb);
        asm volatile("s_waitcnt vmcnt(6)" ::: "memory");
        __builtin_amdgcn_s_barrier();
        if (++cb == 3) cb = 0;
    }
    compute(cb);
    asm volatile("s_waitcnt vmcnt(0)" ::: "memory");
    __builtin_amdgcn_s_barrier();
    if (++cb == 3) cb = 0;
    compute(cb);

    u16* C = Q + (size_t)(bn >> 2) * ((size_t)M * 1024);
    const int cbase = (rowB0 & 1023) + wn * 64;
    #pragma unroll
    for (int i = 0; i < 4; ++i)
        #pragma unroll
        for (int j = 0; j < 4; ++j) {
            const int r0 = rowA0 + wm * 64 + i * 16 + quad * 4;
            const int c0 = cbase + j * 16 + lm;
            #pragma unroll
            for (int g = 0; g < 4; ++g)
                C[(size_t)(r0 + g) * 1024 + c0] = f2bf(acc[i][j][g]);
        }
}

// S (tri 64x128 blocks -> frag-packed E) + V -> B-frag-packed Vf (tail blocks)
__global__ __launch_bounds__(256)
void k_score_vt(const u16* __restrict__ Q, const u16* __restrict__ Kb,
                u16* __restrict__ Epk, float* __restrict__ rowsum,
                const u16* __restrict__ Vb, u16* __restrict__ Vf,
                int T, int D, float kfac, int nTri)
{
    __shared__ __attribute__((aligned(16))) u16 As[64 * 64];
    __shared__ __attribute__((aligned(16))) u16 Bs[128 * 64];
    __shared__ u16 tt[32][33];
    const int bz = blockIdx.z;

    if ((int)blockIdx.x < nTri) {
        // 64-row tri decode (R0-verified): covers bn <= bm/2
        const int idx = blockIdx.x;
        int w = (int)sqrtf((float)idx + 0.5f);
        while (w * w > idx) --w;
        while ((w + 1) * (w + 1) <= idx) ++w;
        int bm, bn;
        if (idx < w * w + w) { bm = 2 * w - 1; bn = idx - w * w; }
        else                 { bm = 2 * w;     bn = idx - (w * w + w); }
        const int bm128 = bm >> 1;
        const int tile  = bm128 * (bm128 + 1) / 2 + bn;
        u16* Etile = Epk + ((size_t)bz * 136 + tile) * 16384;
        gemm_score(Q + (size_t)bz * T * D, Kb + (size_t)bz * T * D,
                   Etile, rowsum, bm, bn, bz, T, D, kfac, As, Bs);
    } else {
        const int t  = blockIdx.x - nTri;
        const int cx = t & 31;          // D/32 tiles
        const int cy = t >> 5;          // T/32 tiles
        const u16* V = Vb + (size_t)bz * T * D;
        u16*      Vo = Vf + (size_t)bz * ((size_t)D * T);
        const int c0 = cx * 32, r0 = cy * 32;
        const int tx = threadIdx.x & 31, ty = threadIdx.x >> 5;
        #pragma unroll
        for (int s = 0; s < 32; s += 8)
            tt[ty + s][tx] = V[(size_t)(r0 + ty + s) * D + c0 + tx];   // tt[t][d]
        __syncthreads();
        if (threadIdx.x < 128) {
            const int l  = threadIdx.x & 63;
            const int f  = threadIdx.x >> 6;          // which 16-d half
            const int dl = f * 16 + (l & 15);
            const int tb = (l >> 4) * 8;
            union { u16 u[8]; float4 v; } r;
            #pragma unroll
            for (int e = 0; e < 8; ++e) r.u[e] = tt[tb + e][dl];
            const int d16g = cx * 2 + f;
            *reinterpret_cast<float4*>(
                &Vo[(size_t)((d16g * (T / 32) + cy) << 9) + l * 8]) = r.v;
        }
    }
}

// ---------------------------------------------------------------------------
// k_pv2 (R7/R8): NO LDS, NO barriers, depth-2 REGISTER pipeline.
// Two named fragment buffers; loads for step t+1 fly under MFMAs of step t
// (compiler emits counted vmcnt for register loads). 12 loads in flight/wave.
// 64x128 out tile, 4 waves 2x2; per 32-k step: 6 coalesced 1KB frag loads +
// 8 MFMA. R6's single-buffer version measured 66 us @ MfmaUtil 9.8%,
// VGPR=52 (serialized load->drain->mfma); this fixes exactly that.
// ---------------------------------------------------------------------------
__global__ __launch_bounds__(256)
void k_pv2(const u16* __restrict__ Epk, const u16* __restrict__ Vf,
           float* __restrict__ out, const float* __restrict__ rowsum,
           int T, int D)
{
    const int bz   = blockIdx.z;
    const int bm   = (gridDim.y - 1) - blockIdx.y;   // 64-row block, heavy-first
    const int bn   = blockIdx.x;                     // D/128
    const int tid  = threadIdx.x;
    const int lane = tid & 63;
    const int wv   = tid >> 6;
    const int wm   = wv >> 1;
    const int wn   = wv & 1;
    const int lm   = lane & 15;
    const int quad = lane >> 4;

    const int bm128 = bm >> 1;
    const u16* Etri = Epk + ((size_t)bz * 136 + (size_t)bm128 * (bm128 + 1) / 2) * 16384;
    const int r16b  = ((bm & 1) << 2) + wm * 2;      // r16 base within 128-tile
    const int kEnd  = (bm + 1) * 64;                 // multiple of 64
    const u16* vfb  = Vf + (size_t)bz * ((size_t)D * T);
    const int  TS   = T >> 5;                        // kt blocks per d16 row
    const int  d16b = (bn << 3) + (wn << 2);

    f32x4 acc[2][4] = {};

    auto loadf = [&](bf16x8 (&af)[2], bf16x8 (&bf)[4], int k0) {
        const u16* tb = Etri + (size_t)(k0 >> 7) * 16384;
        const int  kk = (k0 >> 5) & 3;
        const int  kt = k0 >> 5;
        #pragma unroll
        for (int i = 0; i < 2; ++i)
            af[i] = *reinterpret_cast<const bf16x8*>(
                &tb[(size_t)((((r16b + i) << 2) + kk) << 9) + lane * 8]);
        #pragma unroll
        for (int j = 0; j < 4; ++j)
            bf[j] = *reinterpret_cast<const bf16x8*>(
                &vfb[(size_t)(((d16b + j) * TS + kt) << 9) + lane * 8]);
    };
    auto mfma8 = [&](bf16x8 (&af)[2], bf16x8 (&bf)[4]) {
        #pragma unroll
        for (int i = 0; i < 2; ++i)
            #pragma unroll
            for (int j = 0; j < 4; ++j)
                acc[i][j] = __builtin_amdgcn_mfma_f32_16x16x32_bf16(af[i], bf[j], acc[i][j], 0, 0, 0);
    };

    bf16x8 a0[2], b0[4], a1[2], b1[4];
    loadf(a0, b0, 0);
    loadf(a1, b1, 32);

    int k = 0;
    #pragma unroll 1
    for (; k + 64 < kEnd; k += 64) {
        mfma8(a0, b0);              // waits its own 6 loads; a1/b1 stay in flight
        loadf(a0, b0, k + 64);      // refill under a1's MFMAs
        mfma8(a1, b1);
        loadf(a1, b1, k + 96);
    }
    mfma8(a0, b0);
    mfma8(a1, b1);

    // epilogue: divide by rowsum, write out (C/D layout col=lm, row=quad*4+g)
    const int rowA0 = bm * 64;
    float* C = out + (size_t)bz * ((size_t)T * D);
    #pragma unroll
    for (int i = 0; i < 2; ++i) {
        const int r0 = rowA0 + wm * 32 + i * 16 + quad * 4;
        float inv[4];
        #pragma unroll
        for (int g = 0; g < 4; ++g)
            inv[g] = 1.f / rowsum[(size_t)bz * T + r0 + g];
        #pragma unroll
        for (int j = 0; j < 4; ++j) {
            const int c0 = (bn << 7) + wn * 64 + j * 16 + lm;
            #pragma unroll
            for (int g = 0; g < 4; ++g)
                C[(size_t)(r0 + g) * D + c0] = acc[i][j][g] * inv[g];
        }
    }
}

// prep: cast_x (blocks [0,nCX)) + W transpose-cast ([nCX,nCX+nW)) + RS zero
__global__ __launch_bounds__(256)
void k_prep(const float* __restrict__ x,
            const float* __restrict__ W0, const float* __restrict__ W1,
            const float* __restrict__ W2,
            u16* __restrict__ Xb, u16* __restrict__ Wt, float* __restrict__ RS,
            int D, int nCX, int nW)
{
    const int bx = blockIdx.x;
    if (bx < nCX) {
        long long i = ((long long)bx * 256 + threadIdx.x) * 8;
        const float4 a = *(const float4*)(x + i);
        const float4 b = *(const float4*)(x + i + 4);
        union { u16 u[8]; float4 v; } r;
        r.u[0] = f2bf(a.x); r.u[1] = f2bf(a.y); r.u[2] = f2bf(a.z); r.u[3] = f2bf(a.w);
        r.u[4] = f2bf(b.x); r.u[5] = f2bf(b.y); r.u[6] = f2bf(b.z); r.u[7] = f2bf(b.w);
        *(float4*)(Xb + i) = r.v;
    } else if (bx < nCX + nW) {
        __shared__ u16 t[32][33];
        const int w  = bx - nCX;
        const int z  = w >> 10;                 // 1024 tiles per matrix (32x32)
        const int rm = w & 1023;
        const float* W = z == 0 ? W0 : (z == 1 ? W1 : W2);
        u16* dst = Wt + (size_t)z * D * D;
        const int c0 = (rm & 31) * 32, r0 = (rm >> 5) * 32;
        const int tx = threadIdx.x & 31, ty = threadIdx.x >> 5;
        #pragma unroll
        for (int s = 0; s < 32; s += 8)
            t[ty + s][tx] = f2bf(W[(size_t)(r0 + ty + s) * D + c0 + tx]);
        __syncthreads();
        #pragma unroll
        for (int s = 0; s < 32; s += 8)
            dst[(size_t)(c0 + ty + s) * D + r0 + tx] = t[tx][ty + s];
    } else {
        const int t = bx - nCX - nW;
        ((float4*)RS)[t * 256 + threadIdx.x] = float4{0.f, 0.f, 0.f, 0.f};
    }
}

extern "C" void kernel_launch(void* const* d_in, const int* in_sizes, int n_in,
                              void* d_out, int out_size, void* d_ws, size_t ws_size,
                              hipStream_t stream)
{
    const int B = 4, T = 2048, D = 1024;
    const float* x  = (const float*)d_in[0];
    const float* Wq = (const float*)d_in[1];
    const float* Wk = (const float*)d_in[2];
    const float* Wv = (const float*)d_in[3];
    float* out = (float*)d_out;

    // Workspace layout (86 MB + 32 KB):
    //   [0,16M)   Xb   bf16 x        (dead after k_qkv2)
    //   [16,22M)  Wt   3 x W^T bf16  (dead after k_qkv2)
    //   [0,17.8M) Epk  frag-packed tri E, 4 x 136 tiles x 32KB (aliases Xb/Wt)
    //   [22,38M)  Q    [38,54M) K    [54,70M) V    [70,86M) Vf (B-frag packed)
    //   [86M,+32K) RS  rowsum fp32
    const size_t nX = (size_t)B * T * D;
    u16* Xb  = (u16*)d_ws;
    u16* Wt  = Xb + nX;
    u16* Epk = (u16*)d_ws;                         // alias over Xb+Wt
    u16* Q   = Wt + 3 * (size_t)D * D;
    u16* Kb  = Q + nX;
    u16* Vb  = Kb + nX;
    u16* Vf  = Vb + nX;
    float* RS = (float*)(Vf + nX);

    const float kfac = 1.4426950408889634f / 32.0f;  // log2(e)/sqrt(d_out)
    const int nTri64 = 272;   // sum_{bm=0..31} (bm/2 + 1), 64-row tri tiles
    const int nCX = (int)(nX / (8 * 256));           // 4096 cast blocks
    const int nW  = 3 * (D / 32) * (D / 32);         // 3072 W-transpose blocks
    const int nRS = (B * T) / (4 * 256);             // 8 RS-zero blocks

    static bool attr_done = false;
    if (!attr_done) {
        (void)hipFuncSetAttribute((const void*)k_qkv2,
                                  hipFuncAttributeMaxDynamicSharedMemorySize,
                                  147456);
        attr_done = true;
    }

    // 1. prep: x-cast + W-transpose-cast + RS zero
    k_prep<<<dim3(nCX + nW + nRS), 256, 0, stream>>>(
        x, Wq, Wk, Wv, Xb, Wt, RS, D, nCX, nW);
    // 2. merged QKV projection, counted-vmcnt triple-buffer
    k_qkv2<<<dim3(3 * D / 256, (B * T) / 128), 512, 147456, stream>>>(
        Xb, Wt, Q, B * T, 3 * D, D);
    // 3. S -> frag-packed tri E (272/batch) + V -> B-frag Vf (2048/batch)
    k_score_vt<<<dim3(nTri64 + (D / 32) * (T / 32), 1, B), 256, 0, stream>>>(
        Q, Kb, Epk, RS, Vb, Vf, T, D, kfac, nTri64);
    // 4. PV: LDS-free fragment-direct GEMM, depth-2 reg pipeline, heavy-first
    k_pv2<<<dim3(D / 128, T / 64, B), 256, 0, stream>>>(
        Epk, Vf, out, RS, T, D);
}

// Round 9
// 242.203 us; speedup vs baseline: 1.0763x; 1.0572x over previous
//
#include <hip/hip_runtime.h>
#include <stdint.h>
#include <math.h>

typedef unsigned short u16;
typedef __bf16 bf16x8 __attribute__((ext_vector_type(8)));
typedef float f32x4 __attribute__((ext_vector_type(4)));

enum { M_SCORE = 1, M_PV = 2 };

// fp32 -> bf16 round-to-nearest-even, bit-level
__device__ __forceinline__ u16 f2bf(float f) {
    union { float f; unsigned int u; } a; a.f = f;
    unsigned int u = a.u;
    u += 0x7FFFu + ((u >> 16) & 1u);
    return (u16)(u >> 16);
}

__device__ __forceinline__ void async_load16(const void* g, void* l) {
    __builtin_amdgcn_global_load_lds(
        (const __attribute__((address_space(1))) void*)g,
        (__attribute__((address_space(3))) void*)l,
        16, 0, 0);
}

// ---------------------------------------------------------------------------
// gemm_core (R5 = best measured): TBM x 128 tile, KB=64/iter, 4 waves 2x2,
// 2-barrier loop, 24KB LDS @ TBM=64 -> ~6 blocks/CU. Score/PV are at a
// TLP-bound local floor: bigger tiles (R1), issue-early dbuf (R4), packed-E
// frag-direct (R6-R8) all measured neutral-to-worse.
// LDS granule (row,g) at slot g^(row&7); staging permutes the *global*
// granule per lane (verified family: 0 bank conflicts).
// Packed E: 136 lower-tri 128x128 tiles per batch, tile tri(bm128)+bn128.
// M_SCORE: Cv = packed tile base; local row = (rowA0&127)+rl.
// M_PV:    A  = packed row base for bm128; k-tile = k0>>7.
// ---------------------------------------------------------------------------
template<int MODE, int TBM>
__device__ __forceinline__ void gemm_core(
    const u16* __restrict__ A, const u16* __restrict__ Bt,
    void* __restrict__ Cv, float* __restrict__ rowsum,
    int bm, int bn, int bz, int M, int N, int K, float kfac,
    u16* As, u16* Bs)
{
    constexpr int KB  = 64;
    constexpr int NI  = TBM / 32;        // m-frags per wave
    constexpr int ACH = TBM / 32;        // A staging chunks per wave
    constexpr int BCH = 4;               // B staging chunks per wave

    const int tid  = threadIdx.x;
    const int lane = tid & 63;
    const int wv   = tid >> 6;
    const int wm   = wv >> 1;
    const int wn   = wv & 1;

    f32x4 acc[NI][4] = {};

    const int rowA0 = bm * TBM, rowB0 = bn * 128;
    const int lrow  = lane >> 3;
    const int lslot = lane & 7;
    const int sg    = (lslot ^ lrow) * 8;

    int kEnd = K;
    if (MODE == M_PV) { int ke = (bm + 1) * TBM; kEnd = ke < K ? ke : K; }

    const int lm   = lane & 15;
    const int quad = lane >> 4;
    const int rx   = lm & 7;

    for (int k0 = 0; k0 < kEnd; k0 += KB) {
        #pragma unroll
        for (int c = 0; c < ACH; ++c) {
            const int cc  = wv * ACH + c;
            const int row = cc * 8 + lrow;
            const u16* src;
            if (MODE == M_PV)   // packed tri tiles: kt*16384 + localrow*128 + koff
                src = &A[(size_t)(k0 >> 7) * 16384
                         + (size_t)((rowA0 & 127) + row) * 128 + (k0 & 127) + sg];
            else
                src = &A[(size_t)(rowA0 + row) * K + k0 + sg];
            async_load16(src, &As[cc * 512 + lane * 8]);
        }
        #pragma unroll
        for (int c = 0; c < BCH; ++c) {
            const int cc  = wv * BCH + c;
            const int row = cc * 8 + lrow;
            async_load16(&Bt[(size_t)(rowB0 + row) * K + k0 + sg], &Bs[cc * 512 + lane * 8]);
        }
        __syncthreads();

        #pragma unroll
        for (int h = 0; h < 2; ++h) {
            const int sl = (((h * 4 + quad) ^ rx) * 8);
            bf16x8 af[NI], bfr[4];
            #pragma unroll
            for (int i = 0; i < NI; ++i)
                af[i] = *reinterpret_cast<const bf16x8*>(
                    &As[(wm * (TBM / 2) + i * 16 + lm) * KB + sl]);
            #pragma unroll
            for (int j = 0; j < 4; ++j)
                bfr[j] = *reinterpret_cast<const bf16x8*>(
                    &Bs[(wn * 64 + j * 16 + lm) * KB + sl]);
            #pragma unroll
            for (int i = 0; i < NI; ++i)
                #pragma unroll
                for (int j = 0; j < 4; ++j)
                    acc[i][j] = __builtin_amdgcn_mfma_f32_16x16x32_bf16(af[i], bfr[j], acc[i][j], 0, 0, 0);
        }
        __syncthreads();
    }

    // Epilogue. C/D layout (m89-verified): col = lane&15, row = quad*4 + reg.
    if (MODE == M_SCORE) {
        u16* E = (u16*)Cv;               // packed 128x128 tile, row-major
        const int rbase = rowA0 & 127;   // row offset inside packed tile
        float rs[NI][4];
        #pragma unroll
        for (int i = 0; i < NI; ++i)
            #pragma unroll
            for (int g = 0; g < 4; ++g) rs[i][g] = 0.f;
        #pragma unroll
        for (int i = 0; i < NI; ++i)
            #pragma unroll
            for (int j = 0; j < 4; ++j) {
                const int rl = wm * (TBM / 2) + i * 16 + quad * 4;   // local row
                const int cl = wn * 64 + j * 16 + lm;                // local col
                const int c  = rowB0 + cl;                           // global col
                #pragma unroll
                for (int g = 0; g < 4; ++g) {
                    const int r = rowA0 + rl + g;                    // global row
                    float e = (c <= r) ? exp2f(acc[i][j][g] * kfac) : 0.f;
                    E[(size_t)(rbase + rl + g) * 128 + cl] = f2bf(e);
                    rs[i][g] += e;
                }
            }
        #pragma unroll
        for (int i = 0; i < NI; ++i)
            #pragma unroll
            for (int g = 0; g < 4; ++g) {
                float v = rs[i][g];
                v += __shfl_xor(v, 1); v += __shfl_xor(v, 2);
                v += __shfl_xor(v, 4); v += __shfl_xor(v, 8);
                rs[i][g] = v;
            }
        if (lm == 0) {
            #pragma unroll
            for (int i = 0; i < NI; ++i)
                #pragma unroll
                for (int g = 0; g < 4; ++g) {
                    const int r = rowA0 + wm * (TBM / 2) + i * 16 + quad * 4 + g;
                    atomicAdd(&rowsum[(size_t)bz * M + r], rs[i][g]);
                }
        }
    } else {  // M_PV
        float* C = (float*)Cv + (size_t)bz * ((size_t)M * N);
        #pragma unroll
        for (int i = 0; i < NI; ++i) {
            const int r0 = rowA0 + wm * (TBM / 2) + i * 16 + quad * 4;
            float inv[4];
            #pragma unroll
            for (int g = 0; g < 4; ++g)
                inv[g] = 1.f / rowsum[(size_t)bz * M + r0 + g];
            #pragma unroll
            for (int j = 0; j < 4; ++j) {
                const int c0 = rowB0 + wn * 64 + j * 16 + lm;
                #pragma unroll
                for (int g = 0; g < 4; ++g)
                    C[(size_t)(r0 + g) * N + c0] = acc[i][j][g] * inv[g];
            }
        }
    }
}

// ---------------------------------------------------------------------------
// k_qkv2: counted-vmcnt triple-buffered GEMM. 128x256 tile, 8 waves, KB=64.
// 3 LDS buffers of 48KB. Measured 61-63 us.
// R9: + XCD-aware chunked block swizzle (T1). Grid = 12x64 = 768 blocks,
// 768 % 8 == 0 -> bijective. Each XCD gets 96 contiguous linear ids
// (= 8 full bm rows), keeping its Xb slice (2MB) + Wt hot in its private L2.
// ---------------------------------------------------------------------------
__global__ __launch_bounds__(512, 2)
void k_qkv2(const u16* __restrict__ Xb, const u16* __restrict__ Wt,
            u16* __restrict__ Q, int M, int N, int K)
{
    extern __shared__ __attribute__((aligned(16))) u16 S[];
    const int tid  = threadIdx.x;
    const int lane = tid & 63;
    const int wv   = tid >> 6;
    const int wm   = wv >> 2;
    const int wn   = wv & 3;

    // XCD swizzle: id -> (id&7)*chunk + id>>3  (bijective: total % 8 == 0)
    const int nbx   = gridDim.x;                       // 12
    const int total = nbx * gridDim.y;                 // 768
    const int id    = blockIdx.y * nbx + blockIdx.x;
    const int swz   = (id & 7) * (total >> 3) + (id >> 3);
    const int bn    = swz % nbx;
    const int bm    = swz / nbx;
    const int rowA0 = bm * 128, rowB0 = bn * 256;

    const int lrow  = lane >> 3;
    const int lslot = lane & 7;
    const int sg    = (lslot ^ lrow) * 8;
    const int lm    = lane & 15;
    const int quad  = lane >> 4;
    const int rx    = lm & 7;

    f32x4 acc[4][4] = {};
    const int nt = K >> 6;

    auto stage = [&](int t, int b) {
        u16* As = S + b * 24576;
        u16* Bs = As + 8192;
        const int k0 = t << 6;
        #pragma unroll
        for (int c = 0; c < 2; ++c) {
            const int cc  = wv * 2 + c;
            const int row = cc * 8 + lrow;
            async_load16(&Xb[(size_t)(rowA0 + row) * K + k0 + sg], &As[cc * 512 + lane * 8]);
        }
        #pragma unroll
        for (int c = 0; c < 4; ++c) {
            const int cc  = wv * 4 + c;
            const int row = cc * 8 + lrow;
            async_load16(&Wt[(size_t)(rowB0 + row) * K + k0 + sg], &Bs[cc * 512 + lane * 8]);
        }
    };

    auto compute = [&](int b) {
        const u16* As = S + b * 24576;
        const u16* Bs = As + 8192;
        #pragma unroll
        for (int h = 0; h < 2; ++h) {
            const int sl = (((h * 4 + quad) ^ rx) * 8);
            bf16x8 af[4], bfr[4];
            #pragma unroll
            for (int i = 0; i < 4; ++i)
                af[i] = *reinterpret_cast<const bf16x8*>(
                    &As[(wm * 64 + i * 16 + lm) * 64 + sl]);
            #pragma unroll
            for (int j = 0; j < 4; ++j)
                bfr[j] = *reinterpret_cast<const bf16x8*>(
                    &Bs[(wn * 64 + j * 16 + lm) * 64 + sl]);
            #pragma unroll
            for (int i = 0; i < 4; ++i)
                #pragma unroll
                for (int j = 0; j < 4; ++j)
                    acc[i][j] = __builtin_amdgcn_mfma_f32_16x16x32_bf16(af[i], bfr[j], acc[i][j], 0, 0, 0);
        }
    };

    stage(0, 0);
    stage(1, 1);
    asm volatile("s_waitcnt vmcnt(6)" ::: "memory");
    __builtin_amdgcn_s_barrier();

    int cb = 0;
    #pragma unroll 1
    for (int t = 0; t < nt - 2; ++t) {
        int sb = cb + 2; if (sb >= 3) sb -= 3;
        stage(t + 2, sb);
        compute(cb);
        asm volatile("s_waitcnt vmcnt(6)" ::: "memory");
        __builtin_amdgcn_s_barrier();
        if (++cb == 3) cb = 0;
    }
    compute(cb);
    asm volatile("s_waitcnt vmcnt(0)" ::: "memory");
    __builtin_amdgcn_s_barrier();
    if (++cb == 3) cb = 0;
    compute(cb);

    u16* C = Q + (size_t)(bn >> 2) * ((size_t)M * 1024);   // which of Q/K/V
    const int cbase = (rowB0 & 1023) + wn * 64;
    #pragma unroll
    for (int i = 0; i < 4; ++i)
        #pragma unroll
        for (int j = 0; j < 4; ++j) {
            const int r0 = rowA0 + wm * 64 + i * 16 + quad * 4;
            const int c0 = cbase + j * 16 + lm;
            #pragma unroll
            for (int g = 0; g < 4; ++g)
                C[(size_t)(r0 + g) * 1024 + c0] = f2bf(acc[i][j][g]);
        }
}

// S (tri 64x128 blocks, packed E out) + V-transpose (tail-fill blocks).
// Blocks [0, nTri): E = exp2(kfac * Q K^T) causal + rowsum.
// Blocks [nTri, nTri+2048): 32x32 transpose tiles of V -> Vt[b][c][t].
__global__ __launch_bounds__(256)
void k_score_vt(const u16* __restrict__ Q, const u16* __restrict__ Kb,
                u16* __restrict__ Epk, float* __restrict__ rowsum,
                const u16* __restrict__ Vb, u16* __restrict__ Vt,
                int T, int D, float kfac, int nTri)
{
    __shared__ __attribute__((aligned(16))) u16 As[64 * 64];
    __shared__ __attribute__((aligned(16))) u16 Bs[128 * 64];
    __shared__ u16 tt[32][33];
    const int bz = blockIdx.z;

    if ((int)blockIdx.x < nTri) {
        // 64-row tri decode (R0-verified): covers bn <= bm/2
        const int idx = blockIdx.x;
        int w = (int)sqrtf((float)idx + 0.5f);
        while (w * w > idx) --w;
        while ((w + 1) * (w + 1) <= idx) ++w;
        int bm, bn;
        if (idx < w * w + w) { bm = 2 * w - 1; bn = idx - w * w; }
        else                 { bm = 2 * w;     bn = idx - (w * w + w); }
        // packed tile: bm128 = bm>>1; tile index = tri(bm128) + bn
        const int bm128 = bm >> 1;
        const int tile  = bm128 * (bm128 + 1) / 2 + bn;
        u16* Etile = Epk + ((size_t)bz * 136 + tile) * 16384;
        gemm_core<M_SCORE, 64>(Q + (size_t)bz * T * D, Kb + (size_t)bz * T * D,
                               Etile, rowsum, bm, bn, bz, T, T, D, kfac, As, Bs);
    } else {
        const int t  = blockIdx.x - nTri;
        const int cx = t & 31;          // D/32 tiles
        const int cy = t >> 5;          // T/32 tiles
        const u16* V = Vb + (size_t)bz * T * D;
        u16*      Vo = Vt + (size_t)bz * D * T;
        const int c0 = cx * 32, r0 = cy * 32;
        const int tx = threadIdx.x & 31, ty = threadIdx.x >> 5;
        #pragma unroll
        for (int s = 0; s < 32; s += 8)
            tt[ty + s][tx] = V[(size_t)(r0 + ty + s) * D + c0 + tx];
        __syncthreads();
        #pragma unroll
        for (int s = 0; s < 32; s += 8)
            Vo[(size_t)(c0 + ty + s) * T + r0 + tx] = tt[tx][ty + s];
    }
}

// PV: 64x128 tiles, heavy rows (large bm) dispatched FIRST (LPT scheduling)
__global__ __launch_bounds__(256)
void k_pv(const u16* __restrict__ Epk, const u16* __restrict__ Vt,
          float* __restrict__ out, const float* __restrict__ rowsum,
          int T, int D)
{
    __shared__ __attribute__((aligned(16))) u16 As[64 * 64];
    __shared__ __attribute__((aligned(16))) u16 Bs[128 * 64];
    const int bz = blockIdx.z;
    const int bm = (gridDim.y - 1) - blockIdx.y;   // 64-row index, heavy-first
    const int bm128 = bm >> 1;
    const u16* Arow = Epk + ((size_t)bz * 136 + (size_t)bm128 * (bm128 + 1) / 2) * 16384;
    gemm_core<M_PV, 64>(Arow, Vt + (size_t)bz * D * T,
                        out, (float*)rowsum, bm, blockIdx.x, bz,
                        T, D, T, 0.f, As, Bs);
}

// prep: cast_x (blocks [0,nCX)) + W transpose-cast ([nCX,nCX+nW)) + RS zero
__global__ __launch_bounds__(256)
void k_prep(const float* __restrict__ x,
            const float* __restrict__ W0, const float* __restrict__ W1,
            const float* __restrict__ W2,
            u16* __restrict__ Xb, u16* __restrict__ Wt, float* __restrict__ RS,
            int D, int nCX, int nW)
{
    const int bx = blockIdx.x;
    if (bx < nCX) {
        long long i = ((long long)bx * 256 + threadIdx.x) * 8;
        const float4 a = *(const float4*)(x + i);
        const float4 b = *(const float4*)(x + i + 4);
        union { u16 u[8]; float4 v; } r;
        r.u[0] = f2bf(a.x); r.u[1] = f2bf(a.y); r.u[2] = f2bf(a.z); r.u[3] = f2bf(a.w);
        r.u[4] = f2bf(b.x); r.u[5] = f2bf(b.y); r.u[6] = f2bf(b.z); r.u[7] = f2bf(b.w);
        *(float4*)(Xb + i) = r.v;
    } else if (bx < nCX + nW) {
        __shared__ u16 t[32][33];
        const int w  = bx - nCX;
        const int z  = w >> 10;                 // 1024 tiles per matrix (32x32)
        const int rm = w & 1023;
        const float* W = z == 0 ? W0 : (z == 1 ? W1 : W2);
        u16* dst = Wt + (size_t)z * D * D;
        const int c0 = (rm & 31) * 32, r0 = (rm >> 5) * 32;
        const int tx = threadIdx.x & 31, ty = threadIdx.x >> 5;
        #pragma unroll
        for (int s = 0; s < 32; s += 8)
            t[ty + s][tx] = f2bf(W[(size_t)(r0 + ty + s) * D + c0 + tx]);
        __syncthreads();
        #pragma unroll
        for (int s = 0; s < 32; s += 8)
            dst[(size_t)(c0 + ty + s) * D + r0 + tx] = t[tx][ty + s];
    } else {
        const int t = bx - nCX - nW;
        ((float4*)RS)[t * 256 + threadIdx.x] = float4{0.f, 0.f, 0.f, 0.f};
    }
}

extern "C" void kernel_launch(void* const* d_in, const int* in_sizes, int n_in,
                              void* d_out, int out_size, void* d_ws, size_t ws_size,
                              hipStream_t stream)
{
    const int B = 4, T = 2048, D = 1024;
    const float* x  = (const float*)d_in[0];
    const float* Wq = (const float*)d_in[1];
    const float* Wk = (const float*)d_in[2];
    const float* Wv = (const float*)d_in[3];
    float* out = (float*)d_out;

    // Workspace layout (86 MB + 32 KB):
    //   [0,16M)   Xb   bf16 x        (dead after k_qkv2)
    //   [16,22M)  Wt   3 x W^T bf16  (dead after k_qkv2)
    //   [0,17.8M) Epk  packed tri E, 4 x 136 tiles x 32KB  (aliases Xb/Wt)
    //   [22,38M)  Q    [38,54M) K    [54,70M) V    [70,86M) Vt
    //   [86M,+32K) RS  rowsum fp32
    const size_t nX = (size_t)B * T * D;
    u16* Xb  = (u16*)d_ws;
    u16* Wt  = Xb + nX;
    u16* Epk = (u16*)d_ws;                         // alias over Xb+Wt
    u16* Q   = Wt + 3 * (size_t)D * D;
    u16* Kb  = Q + nX;
    u16* Vb  = Kb + nX;
    u16* Vt  = Vb + nX;
    float* RS = (float*)(Vt + nX);

    const float kfac = 1.4426950408889634f / 32.0f;  // log2(e)/sqrt(d_out)
    const int nTri64 = 272;   // sum_{bm=0..31} (bm/2 + 1), 64-row tri tiles
    const int nCX = (int)(nX / (8 * 256));           // 4096 cast blocks
    const int nW  = 3 * (D / 32) * (D / 32);         // 3072 W-transpose blocks
    const int nRS = (B * T) / (4 * 256);             // 8 RS-zero blocks

    static bool attr_done = false;
    if (!attr_done) {
        (void)hipFuncSetAttribute((const void*)k_qkv2,
                                  hipFuncAttributeMaxDynamicSharedMemorySize,
                                  147456);
        attr_done = true;
    }

    // 1. prep: x-cast + W-transpose-cast + RS zero
    k_prep<<<dim3(nCX + nW + nRS), 256, 0, stream>>>(
        x, Wq, Wk, Wv, Xb, Wt, RS, D, nCX, nW);
    // 2. merged QKV projection, counted-vmcnt triple-buffer + XCD swizzle
    k_qkv2<<<dim3(3 * D / 256, (B * T) / 128), 512, 147456, stream>>>(
        Xb, Wt, Q, B * T, 3 * D, D);
    // 3. S -> packed tri E (272 blocks/batch, 64-row) + V-transpose tail
    k_score_vt<<<dim3(nTri64 + (D / 32) * (T / 32), 1, B), 256, 0, stream>>>(
        Q, Kb, Epk, RS, Vb, Vt, T, D, kfac, nTri64);
    // 4. PV from packed E, 64-row tiles, heavy-first
    k_pv<<<dim3(D / 128, T / 64, B), 256, 0, stream>>>(
        Epk, Vt, out, RS, T, D);
}

// Round 10
// 238.755 us; speedup vs baseline: 1.0918x; 1.0144x over previous
//
#include <hip/hip_runtime.h>
#include <stdint.h>
#include <math.h>

typedef unsigned short u16;
typedef __bf16 bf16x8 __attribute__((ext_vector_type(8)));
typedef float f32x4 __attribute__((ext_vector_type(4)));

enum { M_SCORE = 1, M_PV = 2 };

// fp32 -> bf16 round-to-nearest-even, bit-level
__device__ __forceinline__ u16 f2bf(float f) {
    union { float f; unsigned int u; } a; a.f = f;
    unsigned int u = a.u;
    u += 0x7FFFu + ((u >> 16) & 1u);
    return (u16)(u >> 16);
}

__device__ __forceinline__ void async_load16(const void* g, void* l) {
    __builtin_amdgcn_global_load_lds(
        (const __attribute__((address_space(1))) void*)g,
        (__attribute__((address_space(3))) void*)l,
        16, 0, 0);
}

// ---------------------------------------------------------------------------
// gemm_core (R5 = best measured): TBM x 128 tile, KB=64/iter, 4 waves 2x2,
// 2-barrier loop, 24KB LDS @ TBM=64 -> ~6 blocks/CU. Score/PV are at a
// TLP-bound local floor: bigger tiles (R1), issue-early dbuf (R4), packed-E
// frag-direct (R6-R8) all measured neutral-to-worse.
// LDS granule (row,g) at slot g^(row&7); staging permutes the *global*
// granule per lane (verified family: 0 bank conflicts).
// Packed E: 136 lower-tri 128x128 tiles per batch, tile tri(bm128)+bn128.
// M_SCORE: Cv = packed tile base; local row = (rowA0&127)+rl.
// M_PV:    A  = packed row base for bm128; k-tile = k0>>7.
// ---------------------------------------------------------------------------
template<int MODE, int TBM>
__device__ __forceinline__ void gemm_core(
    const u16* __restrict__ A, const u16* __restrict__ Bt,
    void* __restrict__ Cv, float* __restrict__ rowsum,
    int bm, int bn, int bz, int M, int N, int K, float kfac,
    u16* As, u16* Bs)
{
    constexpr int KB  = 64;
    constexpr int NI  = TBM / 32;        // m-frags per wave
    constexpr int ACH = TBM / 32;        // A staging chunks per wave
    constexpr int BCH = 4;               // B staging chunks per wave

    const int tid  = threadIdx.x;
    const int lane = tid & 63;
    const int wv   = tid >> 6;
    const int wm   = wv >> 1;
    const int wn   = wv & 1;

    f32x4 acc[NI][4] = {};

    const int rowA0 = bm * TBM, rowB0 = bn * 128;
    const int lrow  = lane >> 3;
    const int lslot = lane & 7;
    const int sg    = (lslot ^ lrow) * 8;

    int kEnd = K;
    if (MODE == M_PV) { int ke = (bm + 1) * TBM; kEnd = ke < K ? ke : K; }

    const int lm   = lane & 15;
    const int quad = lane >> 4;
    const int rx   = lm & 7;

    for (int k0 = 0; k0 < kEnd; k0 += KB) {
        #pragma unroll
        for (int c = 0; c < ACH; ++c) {
            const int cc  = wv * ACH + c;
            const int row = cc * 8 + lrow;
            const u16* src;
            if (MODE == M_PV)   // packed tri tiles: kt*16384 + localrow*128 + koff
                src = &A[(size_t)(k0 >> 7) * 16384
                         + (size_t)((rowA0 & 127) + row) * 128 + (k0 & 127) + sg];
            else
                src = &A[(size_t)(rowA0 + row) * K + k0 + sg];
            async_load16(src, &As[cc * 512 + lane * 8]);
        }
        #pragma unroll
        for (int c = 0; c < BCH; ++c) {
            const int cc  = wv * BCH + c;
            const int row = cc * 8 + lrow;
            async_load16(&Bt[(size_t)(rowB0 + row) * K + k0 + sg], &Bs[cc * 512 + lane * 8]);
        }
        __syncthreads();

        #pragma unroll
        for (int h = 0; h < 2; ++h) {
            const int sl = (((h * 4 + quad) ^ rx) * 8);
            bf16x8 af[NI], bfr[4];
            #pragma unroll
            for (int i = 0; i < NI; ++i)
                af[i] = *reinterpret_cast<const bf16x8*>(
                    &As[(wm * (TBM / 2) + i * 16 + lm) * KB + sl]);
            #pragma unroll
            for (int j = 0; j < 4; ++j)
                bfr[j] = *reinterpret_cast<const bf16x8*>(
                    &Bs[(wn * 64 + j * 16 + lm) * KB + sl]);
            #pragma unroll
            for (int i = 0; i < NI; ++i)
                #pragma unroll
                for (int j = 0; j < 4; ++j)
                    acc[i][j] = __builtin_amdgcn_mfma_f32_16x16x32_bf16(af[i], bfr[j], acc[i][j], 0, 0, 0);
        }
        __syncthreads();
    }

    // Epilogue. C/D layout (m89-verified): col = lane&15, row = quad*4 + reg.
    if (MODE == M_SCORE) {
        u16* E = (u16*)Cv;               // packed 128x128 tile, row-major
        const int rbase = rowA0 & 127;   // row offset inside packed tile
        float rs[NI][4];
        #pragma unroll
        for (int i = 0; i < NI; ++i)
            #pragma unroll
            for (int g = 0; g < 4; ++g) rs[i][g] = 0.f;
        #pragma unroll
        for (int i = 0; i < NI; ++i)
            #pragma unroll
            for (int j = 0; j < 4; ++j) {
                const int rl = wm * (TBM / 2) + i * 16 + quad * 4;   // local row
                const int cl = wn * 64 + j * 16 + lm;                // local col
                const int c  = rowB0 + cl;                           // global col
                #pragma unroll
                for (int g = 0; g < 4; ++g) {
                    const int r = rowA0 + rl + g;                    // global row
                    float e = (c <= r) ? exp2f(acc[i][j][g] * kfac) : 0.f;
                    E[(size_t)(rbase + rl + g) * 128 + cl] = f2bf(e);
                    rs[i][g] += e;
                }
            }
        #pragma unroll
        for (int i = 0; i < NI; ++i)
            #pragma unroll
            for (int g = 0; g < 4; ++g) {
                float v = rs[i][g];
                v += __shfl_xor(v, 1); v += __shfl_xor(v, 2);
                v += __shfl_xor(v, 4); v += __shfl_xor(v, 8);
                rs[i][g] = v;
            }
        if (lm == 0) {
            #pragma unroll
            for (int i = 0; i < NI; ++i)
                #pragma unroll
                for (int g = 0; g < 4; ++g) {
                    const int r = rowA0 + wm * (TBM / 2) + i * 16 + quad * 4 + g;
                    atomicAdd(&rowsum[(size_t)bz * M + r], rs[i][g]);
                }
        }
    } else {  // M_PV
        float* C = (float*)Cv + (size_t)bz * ((size_t)M * N);
        #pragma unroll
        for (int i = 0; i < NI; ++i) {
            const int r0 = rowA0 + wm * (TBM / 2) + i * 16 + quad * 4;
            float inv[4];
            #pragma unroll
            for (int g = 0; g < 4; ++g)
                inv[g] = 1.f / rowsum[(size_t)bz * M + r0 + g];
            #pragma unroll
            for (int j = 0; j < 4; ++j) {
                const int c0 = rowB0 + wn * 64 + j * 16 + lm;
                #pragma unroll
                for (int g = 0; g < 4; ++g)
                    C[(size_t)(r0 + g) * N + c0] = acc[i][j][g] * inv[g];
            }
        }
    }
}

// ---------------------------------------------------------------------------
// k_qkv2: counted-vmcnt triple-buffered GEMM. 128x256 tile, 8 waves, KB=64.
// 3 LDS buffers of 48KB. Measured 61-63 us.
// R10: V-output blocks (bn>=8) write Vt[b][d][t] DIRECTLY via an in-block
// LDS transpose (144KB dynamic LDS is idle post-loop): acc -> [d][136]-padded
// tile (8B stores, ~2-way banks = free), barrier, b128 row reads, 256B-
// coalesced global stores. Eliminates the 8192-block V-transpose pass and
// Vb's 16MB write + 16MB read. Values bit-identical (same f2bf).
// ---------------------------------------------------------------------------
__global__ __launch_bounds__(512, 2)
void k_qkv2(const u16* __restrict__ Xb, const u16* __restrict__ Wt,
            u16* __restrict__ Q, u16* __restrict__ Vt, int M, int N, int K)
{
    extern __shared__ __attribute__((aligned(16))) u16 S[];
    const int tid  = threadIdx.x;
    const int lane = tid & 63;
    const int wv   = tid >> 6;
    const int wm   = wv >> 2;
    const int wn   = wv & 3;
    const int bn   = blockIdx.x;
    const int bm   = blockIdx.y;
    const int rowA0 = bm * 128, rowB0 = bn * 256;

    const int lrow  = lane >> 3;
    const int lslot = lane & 7;
    const int sg    = (lslot ^ lrow) * 8;
    const int lm    = lane & 15;
    const int quad  = lane >> 4;
    const int rx    = lm & 7;

    f32x4 acc[4][4] = {};
    const int nt = K >> 6;

    auto stage = [&](int t, int b) {
        u16* As = S + b * 24576;
        u16* Bs = As + 8192;
        const int k0 = t << 6;
        #pragma unroll
        for (int c = 0; c < 2; ++c) {
            const int cc  = wv * 2 + c;
            const int row = cc * 8 + lrow;
            async_load16(&Xb[(size_t)(rowA0 + row) * K + k0 + sg], &As[cc * 512 + lane * 8]);
        }
        #pragma unroll
        for (int c = 0; c < 4; ++c) {
            const int cc  = wv * 4 + c;
            const int row = cc * 8 + lrow;
            async_load16(&Wt[(size_t)(rowB0 + row) * K + k0 + sg], &Bs[cc * 512 + lane * 8]);
        }
    };

    auto compute = [&](int b) {
        const u16* As = S + b * 24576;
        const u16* Bs = As + 8192;
        #pragma unroll
        for (int h = 0; h < 2; ++h) {
            const int sl = (((h * 4 + quad) ^ rx) * 8);
            bf16x8 af[4], bfr[4];
            #pragma unroll
            for (int i = 0; i < 4; ++i)
                af[i] = *reinterpret_cast<const bf16x8*>(
                    &As[(wm * 64 + i * 16 + lm) * 64 + sl]);
            #pragma unroll
            for (int j = 0; j < 4; ++j)
                bfr[j] = *reinterpret_cast<const bf16x8*>(
                    &Bs[(wn * 64 + j * 16 + lm) * 64 + sl]);
            #pragma unroll
            for (int i = 0; i < 4; ++i)
                #pragma unroll
                for (int j = 0; j < 4; ++j)
                    acc[i][j] = __builtin_amdgcn_mfma_f32_16x16x32_bf16(af[i], bfr[j], acc[i][j], 0, 0, 0);
        }
    };

    stage(0, 0);
    stage(1, 1);
    asm volatile("s_waitcnt vmcnt(6)" ::: "memory");
    __builtin_amdgcn_s_barrier();

    int cb = 0;
    #pragma unroll 1
    for (int t = 0; t < nt - 2; ++t) {
        int sb = cb + 2; if (sb >= 3) sb -= 3;
        stage(t + 2, sb);
        compute(cb);
        asm volatile("s_waitcnt vmcnt(6)" ::: "memory");
        __builtin_amdgcn_s_barrier();
        if (++cb == 3) cb = 0;
    }
    compute(cb);
    asm volatile("s_waitcnt vmcnt(0)" ::: "memory");
    __builtin_amdgcn_s_barrier();
    if (++cb == 3) cb = 0;
    compute(cb);

    if (bn < 8) {
        // Q or K: direct row-major store
        u16* C = Q + (size_t)(bn >> 2) * ((size_t)M * 1024);
        const int cbase = (rowB0 & 1023) + wn * 64;
        #pragma unroll
        for (int i = 0; i < 4; ++i)
            #pragma unroll
            for (int j = 0; j < 4; ++j) {
                const int r0 = rowA0 + wm * 64 + i * 16 + quad * 4;
                const int c0 = cbase + j * 16 + lm;
                #pragma unroll
                for (int g = 0; g < 4; ++g)
                    C[(size_t)(r0 + g) * 1024 + c0] = f2bf(acc[i][j][g]);
            }
    } else {
        // V: in-block transpose via LDS [d_local][136] (padded), then
        // coalesced Vt[b][d][t] stores.
        __syncthreads();                 // all waves done with K-loop buffers
        #pragma unroll
        for (int i = 0; i < 4; ++i)
            #pragma unroll
            for (int j = 0; j < 4; ++j) {
                const int d_l = wn * 64 + j * 16 + lm;          // 0..255
                const int t_l = wm * 64 + i * 16 + quad * 4;    // 0..124, mult of 4
                union { u16 u[4]; uint2 v; } p;
                #pragma unroll
                for (int g = 0; g < 4; ++g) p.u[g] = f2bf(acc[i][j][g]);
                *reinterpret_cast<uint2*>(&S[d_l * 136 + t_l]) = p.v;
            }
        __syncthreads();
        const int bzv  = rowA0 >> 11;           // batch (T=2048)
        const int t0   = rowA0 & 2047;
        const int dbs  = (bn & 3) * 256;        // d base within D=1024
        u16* Vo = Vt + (size_t)bzv * (1024u * 2048u);
        #pragma unroll
        for (int it = 0; it < 8; ++it) {
            const int d_l = it * 32 + (tid >> 4);       // 0..255
            const int tp  = (tid & 15) * 8;             // 0..120
            bf16x8 v = *reinterpret_cast<const bf16x8*>(&S[d_l * 136 + tp]);
            *reinterpret_cast<bf16x8*>(
                &Vo[(size_t)(dbs + d_l) * 2048 + t0 + tp]) = v;
        }
    }
}

// S: tri 64x128 blocks only (packed E out). V-transpose now lives in k_qkv2.
__global__ __launch_bounds__(256)
void k_score_vt(const u16* __restrict__ Q, const u16* __restrict__ Kb,
                u16* __restrict__ Epk, float* __restrict__ rowsum,
                int T, int D, float kfac)
{
    __shared__ __attribute__((aligned(16))) u16 As[64 * 64];
    __shared__ __attribute__((aligned(16))) u16 Bs[128 * 64];
    const int bz = blockIdx.z;

    // 64-row tri decode (R0-verified): covers bn <= bm/2
    const int idx = blockIdx.x;
    int w = (int)sqrtf((float)idx + 0.5f);
    while (w * w > idx) --w;
    while ((w + 1) * (w + 1) <= idx) ++w;
    int bm, bn;
    if (idx < w * w + w) { bm = 2 * w - 1; bn = idx - w * w; }
    else                 { bm = 2 * w;     bn = idx - (w * w + w); }
    // packed tile: bm128 = bm>>1; tile index = tri(bm128) + bn
    const int bm128 = bm >> 1;
    const int tile  = bm128 * (bm128 + 1) / 2 + bn;
    u16* Etile = Epk + ((size_t)bz * 136 + tile) * 16384;
    gemm_core<M_SCORE, 64>(Q + (size_t)bz * T * D, Kb + (size_t)bz * T * D,
                           Etile, rowsum, bm, bn, bz, T, T, D, kfac, As, Bs);
}

// PV: 64x128 tiles, heavy rows (large bm) dispatched FIRST (LPT scheduling)
__global__ __launch_bounds__(256)
void k_pv(const u16* __restrict__ Epk, const u16* __restrict__ Vt,
          float* __restrict__ out, const float* __restrict__ rowsum,
          int T, int D)
{
    __shared__ __attribute__((aligned(16))) u16 As[64 * 64];
    __shared__ __attribute__((aligned(16))) u16 Bs[128 * 64];
    const int bz = blockIdx.z;
    const int bm = (gridDim.y - 1) - blockIdx.y;   // 64-row index, heavy-first
    const int bm128 = bm >> 1;
    const u16* Arow = Epk + ((size_t)bz * 136 + (size_t)bm128 * (bm128 + 1) / 2) * 16384;
    gemm_core<M_PV, 64>(Arow, Vt + (size_t)bz * D * T,
                        out, (float*)rowsum, bm, blockIdx.x, bz,
                        T, D, T, 0.f, As, Bs);
}

// prep: cast_x (blocks [0,nCX)) + W transpose-cast ([nCX,nCX+nW)) + RS zero
__global__ __launch_bounds__(256)
void k_prep(const float* __restrict__ x,
            const float* __restrict__ W0, const float* __restrict__ W1,
            const float* __restrict__ W2,
            u16* __restrict__ Xb, u16* __restrict__ Wt, float* __restrict__ RS,
            int D, int nCX, int nW)
{
    const int bx = blockIdx.x;
    if (bx < nCX) {
        long long i = ((long long)bx * 256 + threadIdx.x) * 8;
        const float4 a = *(const float4*)(x + i);
        const float4 b = *(const float4*)(x + i + 4);
        union { u16 u[8]; float4 v; } r;
        r.u[0] = f2bf(a.x); r.u[1] = f2bf(a.y); r.u[2] = f2bf(a.z); r.u[3] = f2bf(a.w);
        r.u[4] = f2bf(b.x); r.u[5] = f2bf(b.y); r.u[6] = f2bf(b.z); r.u[7] = f2bf(b.w);
        *(float4*)(Xb + i) = r.v;
    } else if (bx < nCX + nW) {
        __shared__ u16 t[32][33];
        const int w  = bx - nCX;
        const int z  = w >> 10;                 // 1024 tiles per matrix (32x32)
        const int rm = w & 1023;
        const float* W = z == 0 ? W0 : (z == 1 ? W1 : W2);
        u16* dst = Wt + (size_t)z * D * D;
        const int c0 = (rm & 31) * 32, r0 = (rm >> 5) * 32;
        const int tx = threadIdx.x & 31, ty = threadIdx.x >> 5;
        #pragma unroll
        for (int s = 0; s < 32; s += 8)
            t[ty + s][tx] = f2bf(W[(size_t)(r0 + ty + s) * D + c0 + tx]);
        __syncthreads();
        #pragma unroll
        for (int s = 0; s < 32; s += 8)
            dst[(size_t)(c0 + ty + s) * D + r0 + tx] = t[tx][ty + s];
    } else {
        const int t = bx - nCX - nW;
        ((float4*)RS)[t * 256 + threadIdx.x] = float4{0.f, 0.f, 0.f, 0.f};
    }
}

extern "C" void kernel_launch(void* const* d_in, const int* in_sizes, int n_in,
                              void* d_out, int out_size, void* d_ws, size_t ws_size,
                              hipStream_t stream)
{
    const int B = 4, T = 2048, D = 1024;
    const float* x  = (const float*)d_in[0];
    const float* Wq = (const float*)d_in[1];
    const float* Wk = (const float*)d_in[2];
    const float* Wv = (const float*)d_in[3];
    float* out = (float*)d_out;

    // Workspace layout (86 MB + 32 KB):
    //   [0,16M)   Xb   bf16 x        (dead after k_qkv2)
    //   [16,22M)  Wt   3 x W^T bf16  (dead after k_qkv2)
    //   [0,17.8M) Epk  packed tri E, 4 x 136 tiles x 32KB  (aliases Xb/Wt)
    //   [22,38M)  Q    [38,54M) K    [54,70M) Vb (unused now)  [70,86M) Vt
    //   [86M,+32K) RS  rowsum fp32
    const size_t nX = (size_t)B * T * D;
    u16* Xb  = (u16*)d_ws;
    u16* Wt  = Xb + nX;
    u16* Epk = (u16*)d_ws;                         // alias over Xb+Wt
    u16* Q   = Wt + 3 * (size_t)D * D;
    u16* Kb  = Q + nX;
    u16* Vb  = Kb + nX;                            // slot kept for layout stability
    u16* Vt  = Vb + nX;
    float* RS = (float*)(Vt + nX);

    const float kfac = 1.4426950408889634f / 32.0f;  // log2(e)/sqrt(d_out)
    const int nTri64 = 272;   // sum_{bm=0..31} (bm/2 + 1), 64-row tri tiles
    const int nCX = (int)(nX / (8 * 256));           // 4096 cast blocks
    const int nW  = 3 * (D / 32) * (D / 32);         // 3072 W-transpose blocks
    const int nRS = (B * T) / (4 * 256);             // 8 RS-zero blocks

    static bool attr_done = false;
    if (!attr_done) {
        (void)hipFuncSetAttribute((const void*)k_qkv2,
                                  hipFuncAttributeMaxDynamicSharedMemorySize,
                                  147456);
        attr_done = true;
    }

    // 1. prep: x-cast + W-transpose-cast + RS zero
    k_prep<<<dim3(nCX + nW + nRS), 256, 0, stream>>>(
        x, Wq, Wk, Wv, Xb, Wt, RS, D, nCX, nW);
    // 2. merged QKV projection; V written pre-transposed to Vt in-epilogue
    k_qkv2<<<dim3(3 * D / 256, (B * T) / 128), 512, 147456, stream>>>(
        Xb, Wt, Q, Vt, B * T, 3 * D, D);
    // 3. S -> packed tri E (272 blocks/batch, pure tri grid)
    k_score_vt<<<dim3(nTri64, 1, B), 256, 0, stream>>>(
        Q, Kb, Epk, RS, T, D, kfac);
    // 4. PV from packed E, 64-row tiles, heavy-first
    k_pv<<<dim3(D / 128, T / 64, B), 256, 0, stream>>>(
        Epk, Vt, out, RS, T, D);
}

// Round 11
// 237.007 us; speedup vs baseline: 1.0999x; 1.0074x over previous
//
#include <hip/hip_runtime.h>
#include <stdint.h>
#include <math.h>

typedef unsigned short u16;
typedef __bf16 bf16x8 __attribute__((ext_vector_type(8)));
typedef float f32x4 __attribute__((ext_vector_type(4)));

enum { M_SCORE = 1, M_PV = 2 };

// fp32 -> bf16 round-to-nearest-even, bit-level
__device__ __forceinline__ u16 f2bf(float f) {
    union { float f; unsigned int u; } a; a.f = f;
    unsigned int u = a.u;
    u += 0x7FFFu + ((u >> 16) & 1u);
    return (u16)(u >> 16);
}

__device__ __forceinline__ void async_load16(const void* g, void* l) {
    __builtin_amdgcn_global_load_lds(
        (const __attribute__((address_space(1))) void*)g,
        (__attribute__((address_space(3))) void*)l,
        16, 0, 0);
}

// ---------------------------------------------------------------------------
// gemm_core: TBM x 128 tile, KB=64/iter, 4 waves 2x2, 2-barrier loop.
// Score runs TBM=64 (TLP is its lever: 272 blocks/batch, ~6 blocks/CU).
// PV runs TBM=128 (R11): halves E+Vt traffic (415->284 MB) AND halves
// ds_read_b128 per MFMA (0.75->0.5) — PV's levers are traffic/LDS, not TLP.
// LDS granule (row,g) at slot g^(row&7); staging permutes the *global*
// granule per lane (verified family: 0 bank conflicts).
// Packed E: 136 lower-tri 128x128 tiles per batch, tile tri(bm128)+bn128.
// M_SCORE: Cv = packed tile base; local row = (rowA0&127)+rl.
// M_PV:    A  = packed row base for bm128; k-tile = k0>>7.
// ---------------------------------------------------------------------------
template<int MODE, int TBM>
__device__ __forceinline__ void gemm_core(
    const u16* __restrict__ A, const u16* __restrict__ Bt,
    void* __restrict__ Cv, float* __restrict__ rowsum,
    int bm, int bn, int bz, int M, int N, int K, float kfac,
    u16* As, u16* Bs)
{
    constexpr int KB  = 64;
    constexpr int NI  = TBM / 32;        // m-frags per wave
    constexpr int ACH = TBM / 32;        // A staging chunks per wave
    constexpr int BCH = 4;               // B staging chunks per wave

    const int tid  = threadIdx.x;
    const int lane = tid & 63;
    const int wv   = tid >> 6;
    const int wm   = wv >> 1;
    const int wn   = wv & 1;

    f32x4 acc[NI][4] = {};

    const int rowA0 = bm * TBM, rowB0 = bn * 128;
    const int lrow  = lane >> 3;
    const int lslot = lane & 7;
    const int sg    = (lslot ^ lrow) * 8;

    int kEnd = K;
    if (MODE == M_PV) { int ke = (bm + 1) * TBM; kEnd = ke < K ? ke : K; }

    const int lm   = lane & 15;
    const int quad = lane >> 4;
    const int rx   = lm & 7;

    for (int k0 = 0; k0 < kEnd; k0 += KB) {
        #pragma unroll
        for (int c = 0; c < ACH; ++c) {
            const int cc  = wv * ACH + c;
            const int row = cc * 8 + lrow;
            const u16* src;
            if (MODE == M_PV)   // packed tri tiles: kt*16384 + localrow*128 + koff
                src = &A[(size_t)(k0 >> 7) * 16384
                         + (size_t)((rowA0 & 127) + row) * 128 + (k0 & 127) + sg];
            else
                src = &A[(size_t)(rowA0 + row) * K + k0 + sg];
            async_load16(src, &As[cc * 512 + lane * 8]);
        }
        #pragma unroll
        for (int c = 0; c < BCH; ++c) {
            const int cc  = wv * BCH + c;
            const int row = cc * 8 + lrow;
            async_load16(&Bt[(size_t)(rowB0 + row) * K + k0 + sg], &Bs[cc * 512 + lane * 8]);
        }
        __syncthreads();

        #pragma unroll
        for (int h = 0; h < 2; ++h) {
            const int sl = (((h * 4 + quad) ^ rx) * 8);
            bf16x8 af[NI], bfr[4];
            #pragma unroll
            for (int i = 0; i < NI; ++i)
                af[i] = *reinterpret_cast<const bf16x8*>(
                    &As[(wm * (TBM / 2) + i * 16 + lm) * KB + sl]);
            #pragma unroll
            for (int j = 0; j < 4; ++j)
                bfr[j] = *reinterpret_cast<const bf16x8*>(
                    &Bs[(wn * 64 + j * 16 + lm) * KB + sl]);
            #pragma unroll
            for (int i = 0; i < NI; ++i)
                #pragma unroll
                for (int j = 0; j < 4; ++j)
                    acc[i][j] = __builtin_amdgcn_mfma_f32_16x16x32_bf16(af[i], bfr[j], acc[i][j], 0, 0, 0);
        }
        __syncthreads();
    }

    // Epilogue. C/D layout (m89-verified): col = lane&15, row = quad*4 + reg.
    if (MODE == M_SCORE) {
        u16* E = (u16*)Cv;               // packed 128x128 tile, row-major
        const int rbase = rowA0 & 127;   // row offset inside packed tile
        float rs[NI][4];
        #pragma unroll
        for (int i = 0; i < NI; ++i)
            #pragma unroll
            for (int g = 0; g < 4; ++g) rs[i][g] = 0.f;
        #pragma unroll
        for (int i = 0; i < NI; ++i)
            #pragma unroll
            for (int j = 0; j < 4; ++j) {
                const int rl = wm * (TBM / 2) + i * 16 + quad * 4;   // local row
                const int cl = wn * 64 + j * 16 + lm;                // local col
                const int c  = rowB0 + cl;                           // global col
                #pragma unroll
                for (int g = 0; g < 4; ++g) {
                    const int r = rowA0 + rl + g;                    // global row
                    float e = (c <= r) ? exp2f(acc[i][j][g] * kfac) : 0.f;
                    E[(size_t)(rbase + rl + g) * 128 + cl] = f2bf(e);
                    rs[i][g] += e;
                }
            }
        #pragma unroll
        for (int i = 0; i < NI; ++i)
            #pragma unroll
            for (int g = 0; g < 4; ++g) {
                float v = rs[i][g];
                v += __shfl_xor(v, 1); v += __shfl_xor(v, 2);
                v += __shfl_xor(v, 4); v += __shfl_xor(v, 8);
                rs[i][g] = v;
            }
        if (lm == 0) {
            #pragma unroll
            for (int i = 0; i < NI; ++i)
                #pragma unroll
                for (int g = 0; g < 4; ++g) {
                    const int r = rowA0 + wm * (TBM / 2) + i * 16 + quad * 4 + g;
                    atomicAdd(&rowsum[(size_t)bz * M + r], rs[i][g]);
                }
        }
    } else {  // M_PV
        float* C = (float*)Cv + (size_t)bz * ((size_t)M * N);
        #pragma unroll
        for (int i = 0; i < NI; ++i) {
            const int r0 = rowA0 + wm * (TBM / 2) + i * 16 + quad * 4;
            float inv[4];
            #pragma unroll
            for (int g = 0; g < 4; ++g)
                inv[g] = 1.f / rowsum[(size_t)bz * M + r0 + g];
            #pragma unroll
            for (int j = 0; j < 4; ++j) {
                const int c0 = rowB0 + wn * 64 + j * 16 + lm;
                #pragma unroll
                for (int g = 0; g < 4; ++g)
                    C[(size_t)(r0 + g) * N + c0] = acc[i][j][g] * inv[g];
            }
        }
    }
}

// ---------------------------------------------------------------------------
// k_qkv2: counted-vmcnt triple-buffered GEMM. 128x256 tile, 8 waves, KB=64.
// 3 LDS buffers of 48KB. Measured 61-63 us (R5 config: no XCD swizzle —
// inputs are L3-resident, T1 measured null in R9; V-fusion reverted — R10
// measured it net-negative).
// ---------------------------------------------------------------------------
__global__ __launch_bounds__(512, 2)
void k_qkv2(const u16* __restrict__ Xb, const u16* __restrict__ Wt,
            u16* __restrict__ Q, int M, int N, int K)
{
    extern __shared__ __attribute__((aligned(16))) u16 S[];
    const int tid  = threadIdx.x;
    const int lane = tid & 63;
    const int wv   = tid >> 6;
    const int wm   = wv >> 2;
    const int wn   = wv & 3;
    const int bn   = blockIdx.x;
    const int bm   = blockIdx.y;
    const int rowA0 = bm * 128, rowB0 = bn * 256;

    const int lrow  = lane >> 3;
    const int lslot = lane & 7;
    const int sg    = (lslot ^ lrow) * 8;
    const int lm    = lane & 15;
    const int quad  = lane >> 4;
    const int rx    = lm & 7;

    f32x4 acc[4][4] = {};
    const int nt = K >> 6;

    auto stage = [&](int t, int b) {
        u16* As = S + b * 24576;
        u16* Bs = As + 8192;
        const int k0 = t << 6;
        #pragma unroll
        for (int c = 0; c < 2; ++c) {
            const int cc  = wv * 2 + c;
            const int row = cc * 8 + lrow;
            async_load16(&Xb[(size_t)(rowA0 + row) * K + k0 + sg], &As[cc * 512 + lane * 8]);
        }
        #pragma unroll
        for (int c = 0; c < 4; ++c) {
            const int cc  = wv * 4 + c;
            const int row = cc * 8 + lrow;
            async_load16(&Wt[(size_t)(rowB0 + row) * K + k0 + sg], &Bs[cc * 512 + lane * 8]);
        }
    };

    auto compute = [&](int b) {
        const u16* As = S + b * 24576;
        const u16* Bs = As + 8192;
        #pragma unroll
        for (int h = 0; h < 2; ++h) {
            const int sl = (((h * 4 + quad) ^ rx) * 8);
            bf16x8 af[4], bfr[4];
            #pragma unroll
            for (int i = 0; i < 4; ++i)
                af[i] = *reinterpret_cast<const bf16x8*>(
                    &As[(wm * 64 + i * 16 + lm) * 64 + sl]);
            #pragma unroll
            for (int j = 0; j < 4; ++j)
                bfr[j] = *reinterpret_cast<const bf16x8*>(
                    &Bs[(wn * 64 + j * 16 + lm) * 64 + sl]);
            #pragma unroll
            for (int i = 0; i < 4; ++i)
                #pragma unroll
                for (int j = 0; j < 4; ++j)
                    acc[i][j] = __builtin_amdgcn_mfma_f32_16x16x32_bf16(af[i], bfr[j], acc[i][j], 0, 0, 0);
        }
    };

    stage(0, 0);
    stage(1, 1);
    asm volatile("s_waitcnt vmcnt(6)" ::: "memory");
    __builtin_amdgcn_s_barrier();

    int cb = 0;
    #pragma unroll 1
    for (int t = 0; t < nt - 2; ++t) {
        int sb = cb + 2; if (sb >= 3) sb -= 3;
        stage(t + 2, sb);
        compute(cb);
        asm volatile("s_waitcnt vmcnt(6)" ::: "memory");
        __builtin_amdgcn_s_barrier();
        if (++cb == 3) cb = 0;
    }
    compute(cb);
    asm volatile("s_waitcnt vmcnt(0)" ::: "memory");
    __builtin_amdgcn_s_barrier();
    if (++cb == 3) cb = 0;
    compute(cb);

    u16* C = Q + (size_t)(bn >> 2) * ((size_t)M * 1024);   // which of Q/K/V
    const int cbase = (rowB0 & 1023) + wn * 64;
    #pragma unroll
    for (int i = 0; i < 4; ++i)
        #pragma unroll
        for (int j = 0; j < 4; ++j) {
            const int r0 = rowA0 + wm * 64 + i * 16 + quad * 4;
            const int c0 = cbase + j * 16 + lm;
            #pragma unroll
            for (int g = 0; g < 4; ++g)
                C[(size_t)(r0 + g) * 1024 + c0] = f2bf(acc[i][j][g]);
        }
}

// S (tri 64x128 blocks, packed E out) + V-transpose (tail-fill blocks).
// Blocks [0, nTri): E = exp2(kfac * Q K^T) causal + rowsum.
// Blocks [nTri, nTri+2048): 32x32 transpose tiles of V -> Vt[b][c][t].
__global__ __launch_bounds__(256)
void k_score_vt(const u16* __restrict__ Q, const u16* __restrict__ Kb,
                u16* __restrict__ Epk, float* __restrict__ rowsum,
                const u16* __restrict__ Vb, u16* __restrict__ Vt,
                int T, int D, float kfac, int nTri)
{
    __shared__ __attribute__((aligned(16))) u16 As[64 * 64];
    __shared__ __attribute__((aligned(16))) u16 Bs[128 * 64];
    __shared__ u16 tt[32][33];
    const int bz = blockIdx.z;

    if ((int)blockIdx.x < nTri) {
        // 64-row tri decode (R0-verified): covers bn <= bm/2
        const int idx = blockIdx.x;
        int w = (int)sqrtf((float)idx + 0.5f);
        while (w * w > idx) --w;
        while ((w + 1) * (w + 1) <= idx) ++w;
        int bm, bn;
        if (idx < w * w + w) { bm = 2 * w - 1; bn = idx - w * w; }
        else                 { bm = 2 * w;     bn = idx - (w * w + w); }
        // packed tile: bm128 = bm>>1; tile index = tri(bm128) + bn
        const int bm128 = bm >> 1;
        const int tile  = bm128 * (bm128 + 1) / 2 + bn;
        u16* Etile = Epk + ((size_t)bz * 136 + tile) * 16384;
        gemm_core<M_SCORE, 64>(Q + (size_t)bz * T * D, Kb + (size_t)bz * T * D,
                               Etile, rowsum, bm, bn, bz, T, T, D, kfac, As, Bs);
    } else {
        const int t  = blockIdx.x - nTri;
        const int cx = t & 31;          // D/32 tiles
        const int cy = t >> 5;          // T/32 tiles
        const u16* V = Vb + (size_t)bz * T * D;
        u16*      Vo = Vt + (size_t)bz * D * T;
        const int c0 = cx * 32, r0 = cy * 32;
        const int tx = threadIdx.x & 31, ty = threadIdx.x >> 5;
        #pragma unroll
        for (int s = 0; s < 32; s += 8)
            tt[ty + s][tx] = V[(size_t)(r0 + ty + s) * D + c0 + tx];
        __syncthreads();
        #pragma unroll
        for (int s = 0; s < 32; s += 8)
            Vo[(size_t)(c0 + ty + s) * T + r0 + tx] = tt[tx][ty + s];
    }
}

// PV (R11): 128x128 tiles from packed E, heavy rows dispatched FIRST.
// TBM=128 halves PV's E+Vt input traffic and its LDS-reads-per-MFMA vs the
// 64-row version; score keeps TBM=64 (its lever is TLP).
__global__ __launch_bounds__(256)
void k_pv(const u16* __restrict__ Epk, const u16* __restrict__ Vt,
          float* __restrict__ out, const float* __restrict__ rowsum,
          int T, int D)
{
    __shared__ __attribute__((aligned(16))) u16 As[128 * 64];
    __shared__ __attribute__((aligned(16))) u16 Bs[128 * 64];
    const int bz = blockIdx.z;
    const int bm = (gridDim.y - 1) - blockIdx.y;   // 128-row index, heavy-first
    const u16* Arow = Epk + ((size_t)bz * 136 + (size_t)bm * (bm + 1) / 2) * 16384;
    gemm_core<M_PV, 128>(Arow, Vt + (size_t)bz * D * T,
                         out, (float*)rowsum, bm, blockIdx.x, bz,
                         T, D, T, 0.f, As, Bs);
}

// prep: cast_x (blocks [0,nCX)) + W transpose-cast ([nCX,nCX+nW)) + RS zero
__global__ __launch_bounds__(256)
void k_prep(const float* __restrict__ x,
            const float* __restrict__ W0, const float* __restrict__ W1,
            const float* __restrict__ W2,
            u16* __restrict__ Xb, u16* __restrict__ Wt, float* __restrict__ RS,
            int D, int nCX, int nW)
{
    const int bx = blockIdx.x;
    if (bx < nCX) {
        long long i = ((long long)bx * 256 + threadIdx.x) * 8;
        const float4 a = *(const float4*)(x + i);
        const float4 b = *(const float4*)(x + i + 4);
        union { u16 u[8]; float4 v; } r;
        r.u[0] = f2bf(a.x); r.u[1] = f2bf(a.y); r.u[2] = f2bf(a.z); r.u[3] = f2bf(a.w);
        r.u[4] = f2bf(b.x); r.u[5] = f2bf(b.y); r.u[6] = f2bf(b.z); r.u[7] = f2bf(b.w);
        *(float4*)(Xb + i) = r.v;
    } else if (bx < nCX + nW) {
        __shared__ u16 t[32][33];
        const int w  = bx - nCX;
        const int z  = w >> 10;                 // 1024 tiles per matrix (32x32)
        const int rm = w & 1023;
        const float* W = z == 0 ? W0 : (z == 1 ? W1 : W2);
        u16* dst = Wt + (size_t)z * D * D;
        const int c0 = (rm & 31) * 32, r0 = (rm >> 5) * 32;
        const int tx = threadIdx.x & 31, ty = threadIdx.x >> 5;
        #pragma unroll
        for (int s = 0; s < 32; s += 8)
            t[ty + s][tx] = f2bf(W[(size_t)(r0 + ty + s) * D + c0 + tx]);
        __syncthreads();
        #pragma unroll
        for (int s = 0; s < 32; s += 8)
            dst[(size_t)(c0 + ty + s) * D + r0 + tx] = t[tx][ty + s];
    } else {
        const int t = bx - nCX - nW;
        ((float4*)RS)[t * 256 + threadIdx.x] = float4{0.f, 0.f, 0.f, 0.f};
    }
}

extern "C" void kernel_launch(void* const* d_in, const int* in_sizes, int n_in,
                              void* d_out, int out_size, void* d_ws, size_t ws_size,
                              hipStream_t stream)
{
    const int B = 4, T = 2048, D = 1024;
    const float* x  = (const float*)d_in[0];
    const float* Wq = (const float*)d_in[1];
    const float* Wk = (const float*)d_in[2];
    const float* Wv = (const float*)d_in[3];
    float* out = (float*)d_out;

    // Workspace layout (86 MB + 32 KB):
    //   [0,16M)   Xb   bf16 x        (dead after k_qkv2)
    //   [16,22M)  Wt   3 x W^T bf16  (dead after k_qkv2)
    //   [0,17.8M) Epk  packed tri E, 4 x 136 tiles x 32KB  (aliases Xb/Wt)
    //   [22,38M)  Q    [38,54M) K    [54,70M) V    [70,86M) Vt
    //   [86M,+32K) RS  rowsum fp32
    const size_t nX = (size_t)B * T * D;
    u16* Xb  = (u16*)d_ws;
    u16* Wt  = Xb + nX;
    u16* Epk = (u16*)d_ws;                         // alias over Xb+Wt
    u16* Q   = Wt + 3 * (size_t)D * D;
    u16* Kb  = Q + nX;
    u16* Vb  = Kb + nX;
    u16* Vt  = Vb + nX;
    float* RS = (float*)(Vt + nX);

    const float kfac = 1.4426950408889634f / 32.0f;  // log2(e)/sqrt(d_out)
    const int nTri64 = 272;   // sum_{bm=0..31} (bm/2 + 1), 64-row tri tiles
    const int nCX = (int)(nX / (8 * 256));           // 4096 cast blocks
    const int nW  = 3 * (D / 32) * (D / 32);         // 3072 W-transpose blocks
    const int nRS = (B * T) / (4 * 256);             // 8 RS-zero blocks

    static bool attr_done = false;
    if (!attr_done) {
        (void)hipFuncSetAttribute((const void*)k_qkv2,
                                  hipFuncAttributeMaxDynamicSharedMemorySize,
                                  147456);
        attr_done = true;
    }

    // 1. prep: x-cast + W-transpose-cast + RS zero
    k_prep<<<dim3(nCX + nW + nRS), 256, 0, stream>>>(
        x, Wq, Wk, Wv, Xb, Wt, RS, D, nCX, nW);
    // 2. merged QKV projection, counted-vmcnt triple-buffer
    k_qkv2<<<dim3(3 * D / 256, (B * T) / 128), 512, 147456, stream>>>(
        Xb, Wt, Q, B * T, 3 * D, D);
    // 3. S -> packed tri E (272 blocks/batch, 64-row) + V-transpose tail
    k_score_vt<<<dim3(nTri64 + (D / 32) * (T / 32), 1, B), 256, 0, stream>>>(
        Q, Kb, Epk, RS, Vb, Vt, T, D, kfac, nTri64);
    // 4. PV from packed E, 128-row tiles, heavy-first
    k_pv<<<dim3(D / 128, T / 128, B), 256, 0, stream>>>(
        Epk, Vt, out, RS, T, D);
}